// Round 4
// baseline (498.565 us; speedup 1.0000x reference)
//
#include <hip/hip_runtime.h>
#include <hip/hip_fp16.h>
#include <math.h>

#define NN 50000
#define NE 1600000

typedef unsigned int u32;
typedef _Float16 f16x8 __attribute__((ext_vector_type(8)));
typedef float f32x4 __attribute__((ext_vector_type(4)));

__device__ __forceinline__ float celu_f(float v) {
    return v > 0.0f ? v : expm1f(v);
}

// ======================= sort machinery =======================

__global__ __launch_bounds__(256) void zero_u32_kernel(u32* __restrict__ p, int n) {
    int i = blockIdx.x * 256 + threadIdx.x;
    if (i < n) p[i] = 0u;
}

__global__ __launch_bounds__(256) void hist_kernel(const int* __restrict__ ei,
                                                   u32* __restrict__ cnt) {
    int e = blockIdx.x * 256 + threadIdx.x;
    if (e < NE) atomicAdd(&cnt[ei[NE + e]], 1u);
}

// 3-phase parallel scan: per-block scan -> scan of block sums -> add offsets
__global__ __launch_bounds__(256) void scan1_kernel(const u32* __restrict__ cnt,
                                                    u32* __restrict__ excl,
                                                    u32* __restrict__ bsum) {
    __shared__ u32 s[256];
    const int tid = threadIdx.x;
    const int i = blockIdx.x * 256 + tid;
    u32 v = (i < NN) ? cnt[i] : 0u;
    s[tid] = v;
    __syncthreads();
    for (int d = 1; d < 256; d <<= 1) {
        u32 t = (tid >= d) ? s[tid - d] : 0u;
        __syncthreads();
        s[tid] += t;
        __syncthreads();
    }
    if (i < NN) excl[i] = s[tid] - v;
    if (tid == 255) bsum[blockIdx.x] = s[255];
}

__global__ __launch_bounds__(256) void scan2_kernel(u32* __restrict__ bsum,
                                                    u32* __restrict__ bexcl, int nb) {
    __shared__ u32 s[256];
    const int tid = threadIdx.x;
    u32 v = (tid < nb) ? bsum[tid] : 0u;
    s[tid] = v;
    __syncthreads();
    for (int d = 1; d < 256; d <<= 1) {
        u32 t = (tid >= d) ? s[tid - d] : 0u;
        __syncthreads();
        s[tid] += t;
        __syncthreads();
    }
    if (tid < nb) bexcl[tid] = s[tid] - v;
}

__global__ __launch_bounds__(256) void scan3_kernel(const u32* __restrict__ excl,
                                                    const u32* __restrict__ bexcl,
                                                    u32* __restrict__ off,
                                                    u32* __restrict__ cur) {
    const int i = blockIdx.x * 256 + threadIdx.x;
    if (i < NN) {
        u32 o = excl[i] + bexcl[blockIdx.x];
        off[i] = o;
        cur[i] = o;
    }
    if (i == 0) off[NN] = NE;
}

__global__ __launch_bounds__(256) void scatter_kernel(const int* __restrict__ ei,
                                                      u32* __restrict__ cur,
                                                      u32* __restrict__ eid) {
    int e = blockIdx.x * 256 + threadIdx.x;
    if (e < NE) {
        int d = ei[NE + e];
        u32 p = atomicAdd(&cur[d], 1u);
        eid[p] = (u32)e;
    }
}

// ======================= weight prep =======================

// w2t[n][k] = fw2[k][n] as f16 (A-operand, row-major [out-ch][k])
__global__ __launch_bounds__(256) void prep_w2t_kernel(const float* __restrict__ fw2,
                                                       __half* __restrict__ w2t) {
    int i = blockIdx.x * 256 + threadIdx.x;   // 4096
    int k = i >> 6, n = i & 63;
    w2t[n * 64 + k] = __float2half(fw2[k * 64 + n]);
}

// ======================= fused edge kernel (MFMA layer 2) =======================
//
// One thread per SORTED edge slot. Layer 1 (6->64) on VALU with LDS-broadcast
// weights. h -> f16 -> XOR-swizzled LDS tile [256 edges][8 chunks of 16B],
// stored chunk = c ^ (row & 7). Layer 2 (64->64) via mfma_f32_16x16x32_f16:
//   D[ch][edge] = W2^T[ch][k] * h^T[k][edge]
// A-frag: w2t row-major (row = lane&15 = ch tile row, 16B chunk at k-offset
// (lane>>4)*8 + kt*32). B-frag: h row-major from LDS (row = lane&15 = edge).
// D: col = lane&15 = edge, row = (lane>>4)*4 + reg = channel -> each lane owns
// 4 consecutive channels of one edge -> 8B coalesced global store.
__global__ __launch_bounds__(256) void edge_mfma_kernel(
    const float* __restrict__ x, const float* __restrict__ pos,
    const int* __restrict__ ei, const u32* __restrict__ eid,
    const float* __restrict__ fw1, const float* __restrict__ fb1,
    const __half* __restrict__ w2t, const float* __restrict__ fb2,
    __half* __restrict__ msg)
{
    __shared__ __align__(16) float s_w1[6 * 64];
    __shared__ __align__(16) float s_b1[64];
    __shared__ __align__(16) __half s_h[256 * 64];   // 32 KiB, swizzled

    const int tid = threadIdx.x;
    for (int i = tid; i < 6 * 64; i += 256) s_w1[i] = fw1[i];
    if (tid < 64) s_b1[tid] = fb1[tid];
    __syncthreads();

    const int i = blockIdx.x * 256 + tid;   // NE % 256 == 0
    const int e = (int)eid[i];
    const int s = ei[e];
    const int d = ei[NE + e];

    float in[6];
    in[0] = x[s * 3 + 0];
    in[1] = x[s * 3 + 1];
    in[2] = x[s * 3 + 2];
    in[3] = pos[s * 3 + 0] - pos[d * 3 + 0];
    in[4] = pos[s * 3 + 1] - pos[d * 3 + 1];
    in[5] = pos[s * 3 + 2] - pos[d * 3 + 2];

    // layer 1: per-8-channel chunk, celu, cvt f16, swizzled LDS write
#pragma unroll
    for (int c8 = 0; c8 < 8; ++c8) {
        float4 a0 = *(const float4*)&s_b1[c8 * 8];
        float4 a1 = *(const float4*)&s_b1[c8 * 8 + 4];
#pragma unroll
        for (int q = 0; q < 6; ++q) {
            const float iv = in[q];
            float4 w0 = *(const float4*)&s_w1[q * 64 + c8 * 8];
            float4 w1v = *(const float4*)&s_w1[q * 64 + c8 * 8 + 4];
            a0.x = fmaf(iv, w0.x, a0.x);
            a0.y = fmaf(iv, w0.y, a0.y);
            a0.z = fmaf(iv, w0.z, a0.z);
            a0.w = fmaf(iv, w0.w, a0.w);
            a1.x = fmaf(iv, w1v.x, a1.x);
            a1.y = fmaf(iv, w1v.y, a1.y);
            a1.z = fmaf(iv, w1v.z, a1.z);
            a1.w = fmaf(iv, w1v.w, a1.w);
        }
        union { uint4 u; __half2 h2[4]; } pk;
        pk.h2[0] = __floats2half2_rn(celu_f(a0.x), celu_f(a0.y));
        pk.h2[1] = __floats2half2_rn(celu_f(a0.z), celu_f(a0.w));
        pk.h2[2] = __floats2half2_rn(celu_f(a1.x), celu_f(a1.y));
        pk.h2[3] = __floats2half2_rn(celu_f(a1.z), celu_f(a1.w));
        const int sc = c8 ^ (tid & 7);
        *(uint4*)&s_h[(tid << 6) + (sc << 3)] = pk.u;
    }
    __syncthreads();

    // layer 2: MFMA
    const int l = tid & 63;
    const int wbase = tid & 192;         // wave's edge-row base within block
    const int lrow = l & 15;
    const int lhi = l >> 4;

    f16x8 afrag[4][2];
#pragma unroll
    for (int at = 0; at < 4; ++at)
#pragma unroll
        for (int kt = 0; kt < 2; ++kt)
            afrag[at][kt] = *(const f16x8*)(w2t + ((at * 16 + lrow) << 6) + kt * 32 + (lhi << 3));

    f32x4 bias[4];
#pragma unroll
    for (int at = 0; at < 4; ++at)
        bias[at] = *(const f32x4*)(fb2 + at * 16 + (lhi << 2));

    const size_t msgbase = (size_t)blockIdx.x * 256 * 64;
#pragma unroll
    for (int g = 0; g < 4; ++g) {
        const int rb = wbase + g * 16 + lrow;    // edge row within block
        f32x4 acc[4];
#pragma unroll
        for (int at = 0; at < 4; ++at) acc[at] = bias[at];
#pragma unroll
        for (int kt = 0; kt < 2; ++kt) {
            const int sc = (kt * 4 + lhi) ^ (rb & 7);
            f16x8 b = *(const f16x8*)&s_h[(rb << 6) + (sc << 3)];
            acc[0] = __builtin_amdgcn_mfma_f32_16x16x32_f16(afrag[0][kt], b, acc[0], 0, 0, 0);
            acc[1] = __builtin_amdgcn_mfma_f32_16x16x32_f16(afrag[1][kt], b, acc[1], 0, 0, 0);
            acc[2] = __builtin_amdgcn_mfma_f32_16x16x32_f16(afrag[2][kt], b, acc[2], 0, 0, 0);
            acc[3] = __builtin_amdgcn_mfma_f32_16x16x32_f16(afrag[3][kt], b, acc[3], 0, 0, 0);
        }
        __half* mrow = msg + msgbase + (size_t)rb * 64;
#pragma unroll
        for (int at = 0; at < 4; ++at) {
            union { uint2 u; __half2 h2[2]; } pk;
            pk.h2[0] = __floats2half2_rn(acc[at][0], acc[at][1]);
            pk.h2[1] = __floats2half2_rn(acc[at][2], acc[at][3]);
            *(uint2*)(mrow + at * 16 + (lhi << 2)) = pk.u;
        }
    }
}

// ======================= gather =======================

// Half-wave (32 lanes) per node: max-reduce contiguous message segment.
// 0-init == deferred relu + empty-segment semantics.
__global__ __launch_bounds__(256) void gather_kernel(
    const __half* __restrict__ msg, const u32* __restrict__ off,
    float* __restrict__ aggr)
{
    const int n = blockIdx.x * 8 + (threadIdx.x >> 5);
    const int lane = threadIdx.x & 31;
    if (n >= NN) return;
    const u32 b = off[n];
    const u32 t = off[n + 1];
    const __half2* rows = (const __half2*)msg;
    float2 m0 = make_float2(0.f, 0.f);
    float2 m1 = make_float2(0.f, 0.f);
    u32 j = b;
    for (; j + 2 <= t; j += 2) {
        __half2 ha = rows[(size_t)j * 32 + lane];
        __half2 hb = rows[(size_t)(j + 1) * 32 + lane];
        float2 fa = __half22float2(ha);
        float2 fb = __half22float2(hb);
        m0.x = fmaxf(m0.x, fa.x); m0.y = fmaxf(m0.y, fa.y);
        m1.x = fmaxf(m1.x, fb.x); m1.y = fmaxf(m1.y, fb.y);
    }
    if (j < t) {
        float2 fa = __half22float2(rows[(size_t)j * 32 + lane]);
        m0.x = fmaxf(m0.x, fa.x); m0.y = fmaxf(m0.y, fa.y);
    }
    m0.x = fmaxf(m0.x, m1.x); m0.y = fmaxf(m0.y, m1.y);
    *(float2*)&aggr[(size_t)n * 64 + lane * 2] = m0;
}

// ======================= node update MLP =======================

__global__ __launch_bounds__(256) void node_kernel(
    const float* __restrict__ x,
    float* io,   // d_out: aggr in, final out (in place, thread owns its row)
    const float* __restrict__ gw1, const float* __restrict__ gb1,
    const float* __restrict__ gw2, const float* __restrict__ gb2)
{
    __shared__ __align__(16) float s_w1[67 * 64];
    __shared__ __align__(16) float s_b1[64];
    __shared__ __align__(16) float s_w2[64 * 64];
    __shared__ __align__(16) float s_b2[64];

    const int tid = threadIdx.x;
    for (int i = tid; i < 67 * 64; i += 256) s_w1[i] = gw1[i];
    for (int i = tid; i < 64 * 64; i += 256) s_w2[i] = gw2[i];
    if (tid < 64) { s_b1[tid] = gb1[tid]; s_b2[tid] = gb2[tid]; }
    __syncthreads();

    const int n = blockIdx.x * 256 + tid;
    if (n >= NN) return;

    float a[64];
#pragma unroll
    for (int k = 0; k < 64; k += 4) {
        float4 v = *(const float4*)&io[(size_t)n * 64 + k];
        a[k + 0] = v.x; a[k + 1] = v.y; a[k + 2] = v.z; a[k + 3] = v.w;
    }
    float xv[3];
    xv[0] = x[n * 3 + 0];
    xv[1] = x[n * 3 + 1];
    xv[2] = x[n * 3 + 2];

    float u[64];
    for (int j = 0; j < 64; j += 4) {
        float4 acc = *(const float4*)&s_b1[j];
#pragma unroll
        for (int k = 0; k < 64; ++k) {
            float4 w = *(const float4*)&s_w1[k * 64 + j];
            acc.x = fmaf(a[k], w.x, acc.x);
            acc.y = fmaf(a[k], w.y, acc.y);
            acc.z = fmaf(a[k], w.z, acc.z);
            acc.w = fmaf(a[k], w.w, acc.w);
        }
#pragma unroll
        for (int q = 0; q < 3; ++q) {
            float4 w = *(const float4*)&s_w1[(64 + q) * 64 + j];
            acc.x = fmaf(xv[q], w.x, acc.x);
            acc.y = fmaf(xv[q], w.y, acc.y);
            acc.z = fmaf(xv[q], w.z, acc.z);
            acc.w = fmaf(xv[q], w.w, acc.w);
        }
        u[j + 0] = celu_f(acc.x);
        u[j + 1] = celu_f(acc.y);
        u[j + 2] = celu_f(acc.z);
        u[j + 3] = celu_f(acc.w);
    }

    float* orow = &io[(size_t)n * 64];
    for (int j = 0; j < 64; j += 4) {
        float4 acc = *(const float4*)&s_b2[j];
#pragma unroll
        for (int k = 0; k < 64; ++k) {
            float4 w = *(const float4*)&s_w2[k * 64 + j];
            acc.x = fmaf(u[k], w.x, acc.x);
            acc.y = fmaf(u[k], w.y, acc.y);
            acc.z = fmaf(u[k], w.z, acc.z);
            acc.w = fmaf(u[k], w.w, acc.w);
        }
        float4 r;
        r.x = celu_f(acc.x);
        r.y = celu_f(acc.y);
        r.z = celu_f(acc.z);
        r.w = celu_f(acc.w);
        *(float4*)&orow[j] = r;
    }
}

// ======================= fallback (atomic path) =======================

__global__ __launch_bounds__(256) void zero_kernel(float4* __restrict__ p, int n4) {
    int i = blockIdx.x * blockDim.x + threadIdx.x;
    if (i < n4) p[i] = make_float4(0.f, 0.f, 0.f, 0.f);
}

__global__ __launch_bounds__(256) void edge_atomic_kernel(
    const float* __restrict__ x, const float* __restrict__ pos,
    const int* __restrict__ ei,
    const float* __restrict__ fw1, const float* __restrict__ fb1,
    const float* __restrict__ fw2, const float* __restrict__ fb2,
    unsigned int* __restrict__ aggr)
{
    __shared__ __align__(16) float s_w1[6 * 64];
    __shared__ __align__(16) float s_b1[64];
    __shared__ __align__(16) float s_w2[64 * 64];
    __shared__ __align__(16) float s_b2[64];

    const int tid = threadIdx.x;
    for (int i = tid; i < 6 * 64; i += 256) s_w1[i] = fw1[i];
    for (int i = tid; i < 64 * 64; i += 256) s_w2[i] = fw2[i];
    if (tid < 64) { s_b1[tid] = fb1[tid]; s_b2[tid] = fb2[tid]; }
    __syncthreads();

    const int e = blockIdx.x * 256 + tid;
    if (e >= NE) return;

    const int s = ei[e];
    const int d = ei[NE + e];

    float in[6];
    in[0] = x[s * 3 + 0];
    in[1] = x[s * 3 + 1];
    in[2] = x[s * 3 + 2];
    in[3] = pos[s * 3 + 0] - pos[d * 3 + 0];
    in[4] = pos[s * 3 + 1] - pos[d * 3 + 1];
    in[5] = pos[s * 3 + 2] - pos[d * 3 + 2];

    float h[64];
#pragma unroll
    for (int k = 0; k < 64; k += 4) {
        float4 acc = *(const float4*)&s_b1[k];
#pragma unroll
        for (int q = 0; q < 6; ++q) {
            float4 w = *(const float4*)&s_w1[q * 64 + k];
            acc.x = fmaf(in[q], w.x, acc.x);
            acc.y = fmaf(in[q], w.y, acc.y);
            acc.z = fmaf(in[q], w.z, acc.z);
            acc.w = fmaf(in[q], w.w, acc.w);
        }
        h[k + 0] = celu_f(acc.x);
        h[k + 1] = celu_f(acc.y);
        h[k + 2] = celu_f(acc.z);
        h[k + 3] = celu_f(acc.w);
    }

    unsigned int* arow = aggr + (size_t)d * 64;
    for (int o = 0; o < 64; o += 4) {
        float4 acc = *(const float4*)&s_b2[o];
#pragma unroll
        for (int k = 0; k < 64; ++k) {
            float4 w = *(const float4*)&s_w2[k * 64 + o];
            acc.x = fmaf(h[k], w.x, acc.x);
            acc.y = fmaf(h[k], w.y, acc.y);
            acc.z = fmaf(h[k], w.z, acc.z);
            acc.w = fmaf(h[k], w.w, acc.w);
        }
        if (acc.x > 0.f) atomicMax(&arow[o + 0], __float_as_uint(acc.x));
        if (acc.y > 0.f) atomicMax(&arow[o + 1], __float_as_uint(acc.y));
        if (acc.z > 0.f) atomicMax(&arow[o + 2], __float_as_uint(acc.z));
        if (acc.w > 0.f) atomicMax(&arow[o + 3], __float_as_uint(acc.w));
    }
}

// ======================= launcher =======================

extern "C" void kernel_launch(void* const* d_in, const int* in_sizes, int n_in,
                              void* d_out, int out_size, void* d_ws, size_t ws_size,
                              hipStream_t stream) {
    const float* x   = (const float*)d_in[0];
    const float* pos = (const float*)d_in[1];
    const int*   ei  = (const int*)d_in[2];
    const float* fw1 = (const float*)d_in[3];
    const float* fb1 = (const float*)d_in[4];
    const float* fw2 = (const float*)d_in[5];
    const float* fb2 = (const float*)d_in[6];
    const float* gw1 = (const float*)d_in[7];
    const float* gb1 = (const float*)d_in[8];
    const float* gw2 = (const float*)d_in[9];
    const float* gb2 = (const float*)d_in[10];
    float* out = (float*)d_out;

    const int NB = (NN + 255) / 256;   // 196 scan blocks

    auto al = [](size_t v) { return (v + 255) & ~(size_t)255; };
    const size_t o_cnt  = 0;
    const size_t o_excl = al(o_cnt + (size_t)NN * 4);
    const size_t o_off  = al(o_excl + (size_t)NN * 4);
    const size_t o_cur  = al(o_off + (size_t)(NN + 1) * 4);
    const size_t o_bsum = al(o_cur + (size_t)NN * 4);
    const size_t o_bexc = al(o_bsum + (size_t)NB * 4);
    const size_t o_w2t  = al(o_bexc + (size_t)NB * 4);
    const size_t o_eid  = al(o_w2t + (size_t)64 * 64 * 2);
    const size_t o_msg  = al(o_eid + (size_t)NE * 4);
    const size_t need   = o_msg + (size_t)NE * 64 * 2;

    if (ws_size >= need) {
        char* w = (char*)d_ws;
        u32*    cnt  = (u32*)(w + o_cnt);
        u32*    excl = (u32*)(w + o_excl);
        u32*    off  = (u32*)(w + o_off);
        u32*    cur  = (u32*)(w + o_cur);
        u32*    bsum = (u32*)(w + o_bsum);
        u32*    bexc = (u32*)(w + o_bexc);
        __half* w2t  = (__half*)(w + o_w2t);
        u32*    eid  = (u32*)(w + o_eid);
        __half* msg  = (__half*)(w + o_msg);

        zero_u32_kernel<<<NB, 256, 0, stream>>>(cnt, NN);
        prep_w2t_kernel<<<16, 256, 0, stream>>>(fw2, w2t);
        hist_kernel<<<NE / 256, 256, 0, stream>>>(ei, cnt);
        scan1_kernel<<<NB, 256, 0, stream>>>(cnt, excl, bsum);
        scan2_kernel<<<1, 256, 0, stream>>>(bsum, bexc, NB);
        scan3_kernel<<<NB, 256, 0, stream>>>(excl, bexc, off, cur);
        scatter_kernel<<<NE / 256, 256, 0, stream>>>(ei, cur, eid);
        edge_mfma_kernel<<<NE / 256, 256, 0, stream>>>(x, pos, ei, eid,
                                                       fw1, fb1, w2t, fb2, msg);
        gather_kernel<<<(NN + 7) / 8, 256, 0, stream>>>(msg, off, out);
        node_kernel<<<(NN + 255) / 256, 256, 0, stream>>>(x, out, gw1, gb1, gw2, gb2);
    } else {
        // fallback: atomic path (ws too small for message materialization)
        const int n4 = NN * 64 / 4;
        zero_kernel<<<(n4 + 255) / 256, 256, 0, stream>>>((float4*)out, n4);
        edge_atomic_kernel<<<NE / 256, 256, 0, stream>>>(x, pos, ei, fw1, fb1,
                                                         fw2, fb2, (unsigned int*)out);
        node_kernel<<<(NN + 255) / 256, 256, 0, stream>>>(x, out, gw1, gb1, gw2, gb2);
    }
}

// Round 5
// 384.274 us; speedup vs baseline: 1.2974x; 1.2974x over previous
//
#include <hip/hip_runtime.h>
#include <hip/hip_fp16.h>
#include <math.h>

#define NN 50000
#define NE 1600000

typedef unsigned int u32;
typedef unsigned long long u64;
typedef _Float16 f16x8 __attribute__((ext_vector_type(8)));
typedef float f32x4 __attribute__((ext_vector_type(4)));

__device__ __forceinline__ float celu_f(float v) {
    return v > 0.0f ? v : expm1f(v);
}

// ======================= sort machinery =======================

__global__ __launch_bounds__(256) void zero_u32_kernel(u32* __restrict__ p, int n) {
    int i = blockIdx.x * 256 + threadIdx.x;
    if (i < n) p[i] = 0u;
}

__global__ __launch_bounds__(256) void hist_kernel(const int* __restrict__ ei,
                                                   u32* __restrict__ cnt) {
    int e4 = blockIdx.x * 256 + threadIdx.x;
    if (e4 < NE / 4) {
        int4 d4 = *(const int4*)&ei[NE + e4 * 4];
        atomicAdd(&cnt[d4.x], 1u);
        atomicAdd(&cnt[d4.y], 1u);
        atomicAdd(&cnt[d4.z], 1u);
        atomicAdd(&cnt[d4.w], 1u);
    }
}

// 3-phase parallel scan
__global__ __launch_bounds__(256) void scan1_kernel(const u32* __restrict__ cnt,
                                                    u32* __restrict__ excl,
                                                    u32* __restrict__ bsum) {
    __shared__ u32 s[256];
    const int tid = threadIdx.x;
    const int i = blockIdx.x * 256 + tid;
    u32 v = (i < NN) ? cnt[i] : 0u;
    s[tid] = v;
    __syncthreads();
    for (int d = 1; d < 256; d <<= 1) {
        u32 t = (tid >= d) ? s[tid - d] : 0u;
        __syncthreads();
        s[tid] += t;
        __syncthreads();
    }
    if (i < NN) excl[i] = s[tid] - v;
    if (tid == 255) bsum[blockIdx.x] = s[255];
}

__global__ __launch_bounds__(256) void scan2_kernel(u32* __restrict__ bsum,
                                                    u32* __restrict__ bexcl, int nb) {
    __shared__ u32 s[256];
    const int tid = threadIdx.x;
    u32 v = (tid < nb) ? bsum[tid] : 0u;
    s[tid] = v;
    __syncthreads();
    for (int d = 1; d < 256; d <<= 1) {
        u32 t = (tid >= d) ? s[tid - d] : 0u;
        __syncthreads();
        s[tid] += t;
        __syncthreads();
    }
    if (tid < nb) bexcl[tid] = s[tid] - v;
}

__global__ __launch_bounds__(256) void scan3_kernel(const u32* __restrict__ excl,
                                                    const u32* __restrict__ bexcl,
                                                    u32* __restrict__ cur) {
    const int i = blockIdx.x * 256 + threadIdx.x;
    if (i < NN) cur[i] = excl[i] + bexcl[blockIdx.x];
}

// writes packed (src,dst) per sorted slot -> edge kernel reads sequentially
__global__ __launch_bounds__(256) void scatter_kernel(const int* __restrict__ ei,
                                                      u32* __restrict__ cur,
                                                      u64* __restrict__ sd) {
    int e = blockIdx.x * 256 + threadIdx.x;
    if (e < NE) {
        int s = ei[e];
        int d = ei[NE + e];
        u32 p = atomicAdd(&cur[d], 1u);
        sd[p] = (u32)s | ((u64)(u32)d << 32);
    }
}

// ======================= weight prep =======================

// w2t[n][k] = fw2[k][n] as f16 (A-operand, row-major [out-ch][k])
__global__ __launch_bounds__(256) void prep_w2t_kernel(const float* __restrict__ fw2,
                                                       __half* __restrict__ w2t) {
    int i = blockIdx.x * 256 + threadIdx.x;   // 4096
    int k = i >> 6, n = i & 63;
    w2t[n * 64 + k] = __float2half(fw2[k * 64 + n]);
}

// ======================= fused edge+gather kernel =======================
//
// One thread per SORTED edge slot. Layer 1 (6->64) on VALU, h -> f16 into
// XOR-swizzled LDS tile (16B chunks, sc = c8 ^ (tid&7)). Layer 2 via
// mfma_f32_16x16x32_f16 (A = W2^T row-major, B = h rows from LDS). D layout:
// col=lane&15=edge row, row=(lane>>4)*4+reg=channel. Each lane writes its 4-ch
// f16 result back IN PLACE into s_h (8B chunks XOR-swizzled by row&15 ->
// conflict-free; safe: per-wave in-order LDS, rows are wave-private, each row
// read+written within one g-iter). Then in-block segmented max-reduce over the
// sorted dst runs (wave 0 builds segment table via ballot head-scan) and
// atomicMax (skip <=0) into the zero-init'd aggr = relu+segment-max semantics.
__global__ __launch_bounds__(256) void edge_fused_kernel(
    const float* __restrict__ x, const float* __restrict__ pos,
    const u64* __restrict__ sdb,
    const float* __restrict__ fw1, const float* __restrict__ fb1,
    const __half* __restrict__ w2t, const float* __restrict__ fb2,
    u32* __restrict__ aggr)
{
    __shared__ __align__(16) float s_w1[6 * 64];
    __shared__ __align__(16) float s_b1[64];
    __shared__ __align__(16) __half s_h[256 * 64];   // 32 KiB
    __shared__ u32 s_d[256];
    __shared__ u32 s_start[257];
    __shared__ u32 s_nseg;

    const int tid = threadIdx.x;
    for (int i = tid; i < 6 * 64; i += 256) s_w1[i] = fw1[i];
    if (tid < 64) s_b1[tid] = fb1[tid];

    const int i = blockIdx.x * 256 + tid;   // NE % 256 == 0
    const u64 sd = sdb[i];
    const int s = (int)(u32)sd;
    const int d = (int)(u32)(sd >> 32);
    s_d[tid] = (u32)d;

    float in[6];
    in[0] = x[s * 3 + 0];
    in[1] = x[s * 3 + 1];
    in[2] = x[s * 3 + 2];
    in[3] = pos[s * 3 + 0] - pos[d * 3 + 0];
    in[4] = pos[s * 3 + 1] - pos[d * 3 + 1];
    in[5] = pos[s * 3 + 2] - pos[d * 3 + 2];
    __syncthreads();   // s_w1/s_b1 ready

    // layer 1: per-8-channel chunk, celu, cvt f16, swizzled LDS write
#pragma unroll
    for (int c8 = 0; c8 < 8; ++c8) {
        float4 a0 = *(const float4*)&s_b1[c8 * 8];
        float4 a1 = *(const float4*)&s_b1[c8 * 8 + 4];
#pragma unroll
        for (int q = 0; q < 6; ++q) {
            const float iv = in[q];
            float4 w0 = *(const float4*)&s_w1[q * 64 + c8 * 8];
            float4 w1v = *(const float4*)&s_w1[q * 64 + c8 * 8 + 4];
            a0.x = fmaf(iv, w0.x, a0.x);
            a0.y = fmaf(iv, w0.y, a0.y);
            a0.z = fmaf(iv, w0.z, a0.z);
            a0.w = fmaf(iv, w0.w, a0.w);
            a1.x = fmaf(iv, w1v.x, a1.x);
            a1.y = fmaf(iv, w1v.y, a1.y);
            a1.z = fmaf(iv, w1v.z, a1.z);
            a1.w = fmaf(iv, w1v.w, a1.w);
        }
        union { uint4 u; __half2 h2[4]; } pk;
        pk.h2[0] = __floats2half2_rn(celu_f(a0.x), celu_f(a0.y));
        pk.h2[1] = __floats2half2_rn(celu_f(a0.z), celu_f(a0.w));
        pk.h2[2] = __floats2half2_rn(celu_f(a1.x), celu_f(a1.y));
        pk.h2[3] = __floats2half2_rn(celu_f(a1.z), celu_f(a1.w));
        const int sc = c8 ^ (tid & 7);
        *(uint4*)&s_h[(tid << 6) + (sc << 3)] = pk.u;
    }
    __syncthreads();   // s_h (h) + s_d ready

    // wave 0: segment head-scan over sorted dst -> s_start[0..nseg], terminator
    if (tid < 64) {
        u32 base = 0;
        for (int c = 0; c < 4; ++c) {
            const int t = c * 64 + tid;
            const bool head = (t == 0) || (s_d[t] != s_d[t - 1]);
            const u64 m = __ballot(head);
            const u32 pos0 = base + (u32)__popcll(m & ((1ull << tid) - 1ull));
            if (head) s_start[pos0] = (u32)t;
            base += (u32)__popcll(m);
        }
        if (tid == 0) { s_nseg = base; s_start[base] = 256u; }
    }

    // layer 2: MFMA, write result back in place (swizzled 8B chunks)
    const int l = tid & 63;
    const int wbase = tid & 192;
    const int lrow = l & 15;
    const int lhi = l >> 4;

    f16x8 afrag[4][2];
#pragma unroll
    for (int at = 0; at < 4; ++at)
#pragma unroll
        for (int kt = 0; kt < 2; ++kt)
            afrag[at][kt] = *(const f16x8*)(w2t + ((at * 16 + lrow) << 6) + kt * 32 + (lhi << 3));

    f32x4 bias[4];
#pragma unroll
    for (int at = 0; at < 4; ++at)
        bias[at] = *(const f32x4*)(fb2 + at * 16 + (lhi << 2));

#pragma unroll
    for (int g = 0; g < 4; ++g) {
        const int rb = wbase + g * 16 + lrow;    // edge row within block
        f32x4 acc[4];
#pragma unroll
        for (int at = 0; at < 4; ++at) acc[at] = bias[at];
#pragma unroll
        for (int kt = 0; kt < 2; ++kt) {
            const int sc = (kt * 4 + lhi) ^ (rb & 7);
            f16x8 b = *(const f16x8*)&s_h[(rb << 6) + (sc << 3)];
            acc[0] = __builtin_amdgcn_mfma_f32_16x16x32_f16(afrag[0][kt], b, acc[0], 0, 0, 0);
            acc[1] = __builtin_amdgcn_mfma_f32_16x16x32_f16(afrag[1][kt], b, acc[1], 0, 0, 0);
            acc[2] = __builtin_amdgcn_mfma_f32_16x16x32_f16(afrag[2][kt], b, acc[2], 0, 0, 0);
            acc[3] = __builtin_amdgcn_mfma_f32_16x16x32_f16(afrag[3][kt], b, acc[3], 0, 0, 0);
        }
#pragma unroll
        for (int at = 0; at < 4; ++at) {
            const int c8b = (at * 4 + lhi) ^ (rb & 15);   // 8B-chunk index, swizzled
            union { uint2 u; __half2 h2[2]; } pk;
            pk.h2[0] = __floats2half2_rn(acc[at][0], acc[at][1]);
            pk.h2[1] = __floats2half2_rn(acc[at][2], acc[at][3]);
            *(uint2*)&s_h[(rb << 6) + (c8b << 2)] = pk.u;
        }
    }
    __syncthreads();   // messages + segment table ready

    // segmented max-reduce: half-wave per segment, lane = half2 channel
    const int hw = tid >> 5;
    const int lane2 = tid & 31;
    const u32 nseg = s_nseg;
    for (u32 j = (u32)hw; j < nseg; j += 8) {
        const u32 lo = s_start[j];
        const u32 hi = s_start[j + 1];
        const u32 node = s_d[lo];
        float2 m = make_float2(0.f, 0.f);
        for (u32 r = lo; r < hi; ++r) {
            const u32 c8b = ((u32)(lane2 >> 1)) ^ (r & 15u);
            __half2 hv = *(const __half2*)&s_h[(r << 6) + (c8b << 2) + ((lane2 & 1) << 1)];
            float2 f = __half22float2(hv);
            m.x = fmaxf(m.x, f.x);
            m.y = fmaxf(m.y, f.y);
        }
        u32* arow = aggr + (size_t)node * 64 + lane2 * 2;
        if (m.x > 0.f) atomicMax(&arow[0], __float_as_uint(m.x));
        if (m.y > 0.f) atomicMax(&arow[1], __float_as_uint(m.y));
    }
}

// ======================= node update MLP =======================

__global__ __launch_bounds__(256) void node_kernel(
    const float* __restrict__ x,
    float* io,   // d_out: aggr in, final out (in place, thread owns its row)
    const float* __restrict__ gw1, const float* __restrict__ gb1,
    const float* __restrict__ gw2, const float* __restrict__ gb2)
{
    __shared__ __align__(16) float s_w1[67 * 64];
    __shared__ __align__(16) float s_b1[64];
    __shared__ __align__(16) float s_w2[64 * 64];
    __shared__ __align__(16) float s_b2[64];

    const int tid = threadIdx.x;
    for (int i = tid; i < 67 * 64; i += 256) s_w1[i] = gw1[i];
    for (int i = tid; i < 64 * 64; i += 256) s_w2[i] = gw2[i];
    if (tid < 64) { s_b1[tid] = gb1[tid]; s_b2[tid] = gb2[tid]; }
    __syncthreads();

    const int n = blockIdx.x * 256 + tid;
    if (n >= NN) return;

    float a[64];
#pragma unroll
    for (int k = 0; k < 64; k += 4) {
        float4 v = *(const float4*)&io[(size_t)n * 64 + k];
        a[k + 0] = v.x; a[k + 1] = v.y; a[k + 2] = v.z; a[k + 3] = v.w;
    }
    float xv[3];
    xv[0] = x[n * 3 + 0];
    xv[1] = x[n * 3 + 1];
    xv[2] = x[n * 3 + 2];

    float u[64];
    for (int j = 0; j < 64; j += 4) {
        float4 acc = *(const float4*)&s_b1[j];
#pragma unroll
        for (int k = 0; k < 64; ++k) {
            float4 w = *(const float4*)&s_w1[k * 64 + j];
            acc.x = fmaf(a[k], w.x, acc.x);
            acc.y = fmaf(a[k], w.y, acc.y);
            acc.z = fmaf(a[k], w.z, acc.z);
            acc.w = fmaf(a[k], w.w, acc.w);
        }
#pragma unroll
        for (int q = 0; q < 3; ++q) {
            float4 w = *(const float4*)&s_w1[(64 + q) * 64 + j];
            acc.x = fmaf(xv[q], w.x, acc.x);
            acc.y = fmaf(xv[q], w.y, acc.y);
            acc.z = fmaf(xv[q], w.z, acc.z);
            acc.w = fmaf(xv[q], w.w, acc.w);
        }
        u[j + 0] = celu_f(acc.x);
        u[j + 1] = celu_f(acc.y);
        u[j + 2] = celu_f(acc.z);
        u[j + 3] = celu_f(acc.w);
    }

    float* orow = &io[(size_t)n * 64];
    for (int j = 0; j < 64; j += 4) {
        float4 acc = *(const float4*)&s_b2[j];
#pragma unroll
        for (int k = 0; k < 64; ++k) {
            float4 w = *(const float4*)&s_w2[k * 64 + j];
            acc.x = fmaf(u[k], w.x, acc.x);
            acc.y = fmaf(u[k], w.y, acc.y);
            acc.z = fmaf(u[k], w.z, acc.z);
            acc.w = fmaf(u[k], w.w, acc.w);
        }
        float4 r;
        r.x = celu_f(acc.x);
        r.y = celu_f(acc.y);
        r.z = celu_f(acc.z);
        r.w = celu_f(acc.w);
        *(float4*)&orow[j] = r;
    }
}

// ======================= fallback (atomic path) =======================

__global__ __launch_bounds__(256) void zero_kernel(float4* __restrict__ p, int n4) {
    int i = blockIdx.x * blockDim.x + threadIdx.x;
    if (i < n4) p[i] = make_float4(0.f, 0.f, 0.f, 0.f);
}

__global__ __launch_bounds__(256) void edge_atomic_kernel(
    const float* __restrict__ x, const float* __restrict__ pos,
    const int* __restrict__ ei,
    const float* __restrict__ fw1, const float* __restrict__ fb1,
    const float* __restrict__ fw2, const float* __restrict__ fb2,
    unsigned int* __restrict__ aggr)
{
    __shared__ __align__(16) float s_w1[6 * 64];
    __shared__ __align__(16) float s_b1[64];
    __shared__ __align__(16) float s_w2[64 * 64];
    __shared__ __align__(16) float s_b2[64];

    const int tid = threadIdx.x;
    for (int i = tid; i < 6 * 64; i += 256) s_w1[i] = fw1[i];
    for (int i = tid; i < 64 * 64; i += 256) s_w2[i] = fw2[i];
    if (tid < 64) { s_b1[tid] = fb1[tid]; s_b2[tid] = fb2[tid]; }
    __syncthreads();

    const int e = blockIdx.x * 256 + tid;
    if (e >= NE) return;

    const int s = ei[e];
    const int d = ei[NE + e];

    float in[6];
    in[0] = x[s * 3 + 0];
    in[1] = x[s * 3 + 1];
    in[2] = x[s * 3 + 2];
    in[3] = pos[s * 3 + 0] - pos[d * 3 + 0];
    in[4] = pos[s * 3 + 1] - pos[d * 3 + 1];
    in[5] = pos[s * 3 + 2] - pos[d * 3 + 2];

    float h[64];
#pragma unroll
    for (int k = 0; k < 64; k += 4) {
        float4 acc = *(const float4*)&s_b1[k];
#pragma unroll
        for (int q = 0; q < 6; ++q) {
            float4 w = *(const float4*)&s_w1[q * 64 + k];
            acc.x = fmaf(in[q], w.x, acc.x);
            acc.y = fmaf(in[q], w.y, acc.y);
            acc.z = fmaf(in[q], w.z, acc.z);
            acc.w = fmaf(in[q], w.w, acc.w);
        }
        h[k + 0] = celu_f(acc.x);
        h[k + 1] = celu_f(acc.y);
        h[k + 2] = celu_f(acc.z);
        h[k + 3] = celu_f(acc.w);
    }

    unsigned int* arow = aggr + (size_t)d * 64;
    for (int o = 0; o < 64; o += 4) {
        float4 acc = *(const float4*)&s_b2[o];
#pragma unroll
        for (int k = 0; k < 64; ++k) {
            float4 w = *(const float4*)&s_w2[k * 64 + o];
            acc.x = fmaf(h[k], w.x, acc.x);
            acc.y = fmaf(h[k], w.y, acc.y);
            acc.z = fmaf(h[k], w.z, acc.z);
            acc.w = fmaf(h[k], w.w, acc.w);
        }
        if (acc.x > 0.f) atomicMax(&arow[o + 0], __float_as_uint(acc.x));
        if (acc.y > 0.f) atomicMax(&arow[o + 1], __float_as_uint(acc.y));
        if (acc.z > 0.f) atomicMax(&arow[o + 2], __float_as_uint(acc.z));
        if (acc.w > 0.f) atomicMax(&arow[o + 3], __float_as_uint(acc.w));
    }
}

// ======================= launcher =======================

extern "C" void kernel_launch(void* const* d_in, const int* in_sizes, int n_in,
                              void* d_out, int out_size, void* d_ws, size_t ws_size,
                              hipStream_t stream) {
    const float* x   = (const float*)d_in[0];
    const float* pos = (const float*)d_in[1];
    const int*   ei  = (const int*)d_in[2];
    const float* fw1 = (const float*)d_in[3];
    const float* fb1 = (const float*)d_in[4];
    const float* fw2 = (const float*)d_in[5];
    const float* fb2 = (const float*)d_in[6];
    const float* gw1 = (const float*)d_in[7];
    const float* gb1 = (const float*)d_in[8];
    const float* gw2 = (const float*)d_in[9];
    const float* gb2 = (const float*)d_in[10];
    float* out = (float*)d_out;

    const int NB = (NN + 255) / 256;   // 196 scan blocks
    const int n4 = NN * 64 / 4;

    auto al = [](size_t v) { return (v + 255) & ~(size_t)255; };
    const size_t o_cnt  = 0;
    const size_t o_excl = al(o_cnt + (size_t)NN * 4);
    const size_t o_cur  = al(o_excl + (size_t)NN * 4);
    const size_t o_bsum = al(o_cur + (size_t)NN * 4);
    const size_t o_bexc = al(o_bsum + (size_t)NB * 4);
    const size_t o_w2t  = al(o_bexc + (size_t)NB * 4);
    const size_t o_sd   = al(o_w2t + (size_t)64 * 64 * 2);
    const size_t need   = o_sd + (size_t)NE * 8;

    if (ws_size >= need) {
        char* w = (char*)d_ws;
        u32*    cnt  = (u32*)(w + o_cnt);
        u32*    excl = (u32*)(w + o_excl);
        u32*    cur  = (u32*)(w + o_cur);
        u32*    bsum = (u32*)(w + o_bsum);
        u32*    bexc = (u32*)(w + o_bexc);
        __half* w2t  = (__half*)(w + o_w2t);
        u64*    sd   = (u64*)(w + o_sd);

        zero_kernel<<<(n4 + 255) / 256, 256, 0, stream>>>((float4*)out, n4);
        zero_u32_kernel<<<NB, 256, 0, stream>>>(cnt, NN);
        prep_w2t_kernel<<<16, 256, 0, stream>>>(fw2, w2t);
        hist_kernel<<<(NE / 4 + 255) / 256, 256, 0, stream>>>(ei, cnt);
        scan1_kernel<<<NB, 256, 0, stream>>>(cnt, excl, bsum);
        scan2_kernel<<<1, 256, 0, stream>>>(bsum, bexc, NB);
        scan3_kernel<<<NB, 256, 0, stream>>>(excl, bexc, cur);
        scatter_kernel<<<NE / 256, 256, 0, stream>>>(ei, cur, sd);
        edge_fused_kernel<<<NE / 256, 256, 0, stream>>>(x, pos, sd, fw1, fb1,
                                                        w2t, fb2, (u32*)out);
        node_kernel<<<(NN + 255) / 256, 256, 0, stream>>>(x, out, gw1, gb1, gw2, gb2);
    } else {
        // fallback: atomic path (ws too small)
        zero_kernel<<<(n4 + 255) / 256, 256, 0, stream>>>((float4*)out, n4);
        edge_atomic_kernel<<<NE / 256, 256, 0, stream>>>(x, pos, ei, fw1, fb1,
                                                         fw2, fb2, (unsigned int*)out);
        node_kernel<<<(NN + 255) / 256, 256, 0, stream>>>(x, out, gw1, gb1, gw2, gb2);
    }
}

// Round 6
// 271.195 us; speedup vs baseline: 1.8384x; 1.4170x over previous
//
#include <hip/hip_runtime.h>
#include <hip/hip_fp16.h>
#include <math.h>

#define NN 50000
#define NE 1600000
#define NBKT 98          // ceil(50000 / 512)
#define BKT_SHIFT 9      // 512 nodes per bucket

typedef unsigned int u32;
typedef unsigned long long u64;
typedef _Float16 f16x8 __attribute__((ext_vector_type(8)));
typedef float f32x4 __attribute__((ext_vector_type(4)));

__device__ __forceinline__ float celu_f(float v) {
    return v > 0.0f ? v : expm1f(v);
}

// ======================= bucketed counting sort =======================

// coarse histogram over 98 buckets (dst>>9). 391 blocks x 4096 edges.
__global__ __launch_bounds__(256) void hist_bkt_kernel(const int* __restrict__ ei,
                                                       u32* __restrict__ gcnt) {
    __shared__ u32 s_h[NBKT];
    const int tid = threadIdx.x;
    if (tid < NBKT) s_h[tid] = 0u;
    __syncthreads();
    const int e0 = blockIdx.x * 4096 + tid * 16;
    if (e0 < NE) {
        const int4* dp = (const int4*)&ei[NE + e0];
#pragma unroll
        for (int q = 0; q < 4; ++q) {
            int4 d4 = dp[q];
            atomicAdd(&s_h[d4.x >> BKT_SHIFT], 1u);
            atomicAdd(&s_h[d4.y >> BKT_SHIFT], 1u);
            atomicAdd(&s_h[d4.z >> BKT_SHIFT], 1u);
            atomicAdd(&s_h[d4.w >> BKT_SHIFT], 1u);
        }
    }
    __syncthreads();
    if (tid < NBKT && s_h[tid]) atomicAdd(&gcnt[tid], s_h[tid]);
}

// single small block: exclusive scan of 98 bucket counts -> gbase[0..98], gcur
__global__ __launch_bounds__(128) void scan_bkt_kernel(const u32* __restrict__ gcnt,
                                                       u32* __restrict__ gbase,
                                                       u32* __restrict__ gcur) {
    __shared__ u32 s[128];
    const int tid = threadIdx.x;
    u32 v = (tid < NBKT) ? gcnt[tid] : 0u;
    s[tid] = v;
    __syncthreads();
    for (int d = 1; d < 128; d <<= 1) {
        u32 t = (tid >= d) ? s[tid - d] : 0u;
        __syncthreads();
        s[tid] += t;
        __syncthreads();
    }
    if (tid < NBKT) {
        gbase[tid + 1] = s[tid];
        gcur[tid] = s[tid] - v;
    }
    if (tid == 0) gbase[0] = 0u;
}

// bin edges into bucket-contiguous regions of sd1. Block = 4096 edges; per
// block-bucket one global reservation -> ~42-slot contiguous writes (L2-local).
__global__ __launch_bounds__(256) void binA_kernel(const int* __restrict__ ei,
                                                   u32* __restrict__ gcur,
                                                   u64* __restrict__ sd1) {
    __shared__ u32 s_hist[NBKT];
    __shared__ u32 s_base[NBKT];
    __shared__ u32 s_cur[NBKT];
    const int tid = threadIdx.x;
    if (tid < NBKT) { s_hist[tid] = 0u; s_cur[tid] = 0u; }
    __syncthreads();

    const int e0 = blockIdx.x * 4096 + tid * 16;
    const bool valid = (e0 < NE);
    u64 ed[16];
    if (valid) {
        const int4* sp = (const int4*)&ei[e0];
        const int4* dp = (const int4*)&ei[NE + e0];
#pragma unroll
        for (int q = 0; q < 4; ++q) {
            int4 s4 = sp[q];
            int4 d4 = dp[q];
            ed[q * 4 + 0] = (u32)s4.x | ((u64)(u32)d4.x << 32);
            ed[q * 4 + 1] = (u32)s4.y | ((u64)(u32)d4.y << 32);
            ed[q * 4 + 2] = (u32)s4.z | ((u64)(u32)d4.z << 32);
            ed[q * 4 + 3] = (u32)s4.w | ((u64)(u32)d4.w << 32);
        }
#pragma unroll
        for (int q = 0; q < 16; ++q)
            atomicAdd(&s_hist[(u32)(ed[q] >> 32) >> BKT_SHIFT], 1u);
    }
    __syncthreads();
    if (tid < NBKT && s_hist[tid]) s_base[tid] = atomicAdd(&gcur[tid], s_hist[tid]);
    __syncthreads();
    if (valid) {
#pragma unroll
        for (int q = 0; q < 16; ++q) {
            const u32 b = (u32)(ed[q] >> 32) >> BKT_SHIFT;
            const u32 r = atomicAdd(&s_cur[b], 1u);
            sd1[s_base[b] + r] = ed[q];
        }
    }
}

// exact sort within each bucket (one block per bucket): counting sort by
// dst&511. Writes span only the bucket's ~130KB region -> XCD-L2 resident.
__global__ __launch_bounds__(256) void sortB_kernel(const u64* __restrict__ sd1,
                                                    const u32* __restrict__ gbase,
                                                    u64* __restrict__ sd2) {
    __shared__ u32 s_cnt[512];
    __shared__ u32 s_scan[512];
    const int tid = threadIdx.x;
    const u32 lo = gbase[blockIdx.x];
    const u32 hi = gbase[blockIdx.x + 1];

    s_cnt[tid] = 0u; s_cnt[tid + 256] = 0u;
    __syncthreads();
    for (u32 j = lo + tid; j < hi; j += 256)
        atomicAdd(&s_cnt[(u32)(sd1[j] >> 32) & 511u], 1u);
    __syncthreads();
    s_scan[tid] = s_cnt[tid];
    s_scan[tid + 256] = s_cnt[tid + 256];
    __syncthreads();
    for (int d = 1; d < 512; d <<= 1) {
        const int i0 = tid, i1 = tid + 256;
        u32 a0 = (i0 >= d) ? s_scan[i0 - d] : 0u;
        u32 a1 = (i1 >= d) ? s_scan[i1 - d] : 0u;
        __syncthreads();
        s_scan[i0] += a0;
        s_scan[i1] += a1;
        __syncthreads();
    }
    // exclusive + cursor
    s_scan[tid] -= s_cnt[tid];
    s_scan[tid + 256] -= s_cnt[tid + 256];
    __syncthreads();
    for (u32 j = lo + tid; j < hi; j += 256) {
        const u64 sd = sd1[j];
        const u32 dl = (u32)(sd >> 32) & 511u;
        const u32 r = atomicAdd(&s_scan[dl], 1u);
        sd2[lo + r] = sd;
    }
}

// ======================= weight prep =======================

// w2t[n][k] = fw2[k][n] as f16 (A-operand, row-major [out-ch][k])
__global__ __launch_bounds__(256) void prep_w2t_kernel(const float* __restrict__ fw2,
                                                       __half* __restrict__ w2t) {
    int i = blockIdx.x * 256 + threadIdx.x;   // 4096
    int k = i >> 6, n = i & 63;
    w2t[n * 64 + k] = __float2half(fw2[k * 64 + n]);
}

// ======================= fused edge+gather kernel =======================
//
// One thread per SORTED edge slot. Layer 1 (6->64) on VALU, h -> f16 into
// XOR-swizzled LDS tile. Layer 2 via mfma_f32_16x16x32_f16, result written
// back in place (swizzled 8B chunks). In-block segmented max-reduce over the
// sorted dst runs, then atomicMax (skip <=0) into zero-init'd aggr.
__global__ __launch_bounds__(256) void edge_fused_kernel(
    const float* __restrict__ x, const float* __restrict__ pos,
    const u64* __restrict__ sdb,
    const float* __restrict__ fw1, const float* __restrict__ fb1,
    const __half* __restrict__ w2t, const float* __restrict__ fb2,
    u32* __restrict__ aggr)
{
    __shared__ __align__(16) float s_w1[6 * 64];
    __shared__ __align__(16) float s_b1[64];
    __shared__ __align__(16) __half s_h[256 * 64];   // 32 KiB
    __shared__ u32 s_d[256];
    __shared__ u32 s_start[257];
    __shared__ u32 s_nseg;

    const int tid = threadIdx.x;
    for (int i = tid; i < 6 * 64; i += 256) s_w1[i] = fw1[i];
    if (tid < 64) s_b1[tid] = fb1[tid];

    const int i = blockIdx.x * 256 + tid;   // NE % 256 == 0
    const u64 sd = sdb[i];
    const int s = (int)(u32)sd;
    const int d = (int)(u32)(sd >> 32);
    s_d[tid] = (u32)d;

    float in[6];
    in[0] = x[s * 3 + 0];
    in[1] = x[s * 3 + 1];
    in[2] = x[s * 3 + 2];
    in[3] = pos[s * 3 + 0] - pos[d * 3 + 0];
    in[4] = pos[s * 3 + 1] - pos[d * 3 + 1];
    in[5] = pos[s * 3 + 2] - pos[d * 3 + 2];
    __syncthreads();   // s_w1/s_b1 ready

    // layer 1: per-8-channel chunk, celu, cvt f16, swizzled LDS write
#pragma unroll
    for (int c8 = 0; c8 < 8; ++c8) {
        float4 a0 = *(const float4*)&s_b1[c8 * 8];
        float4 a1 = *(const float4*)&s_b1[c8 * 8 + 4];
#pragma unroll
        for (int q = 0; q < 6; ++q) {
            const float iv = in[q];
            float4 w0 = *(const float4*)&s_w1[q * 64 + c8 * 8];
            float4 w1v = *(const float4*)&s_w1[q * 64 + c8 * 8 + 4];
            a0.x = fmaf(iv, w0.x, a0.x);
            a0.y = fmaf(iv, w0.y, a0.y);
            a0.z = fmaf(iv, w0.z, a0.z);
            a0.w = fmaf(iv, w0.w, a0.w);
            a1.x = fmaf(iv, w1v.x, a1.x);
            a1.y = fmaf(iv, w1v.y, a1.y);
            a1.z = fmaf(iv, w1v.z, a1.z);
            a1.w = fmaf(iv, w1v.w, a1.w);
        }
        union { uint4 u; __half2 h2[4]; } pk;
        pk.h2[0] = __floats2half2_rn(celu_f(a0.x), celu_f(a0.y));
        pk.h2[1] = __floats2half2_rn(celu_f(a0.z), celu_f(a0.w));
        pk.h2[2] = __floats2half2_rn(celu_f(a1.x), celu_f(a1.y));
        pk.h2[3] = __floats2half2_rn(celu_f(a1.z), celu_f(a1.w));
        const int sc = c8 ^ (tid & 7);
        *(uint4*)&s_h[(tid << 6) + (sc << 3)] = pk.u;
    }
    __syncthreads();   // s_h (h) + s_d ready

    // wave 0: segment head-scan over sorted dst -> s_start[0..nseg], terminator
    if (tid < 64) {
        u32 base = 0;
        for (int c = 0; c < 4; ++c) {
            const int t = c * 64 + tid;
            const bool head = (t == 0) || (s_d[t] != s_d[t - 1]);
            const u64 m = __ballot(head);
            const u32 pos0 = base + (u32)__popcll(m & ((1ull << tid) - 1ull));
            if (head) s_start[pos0] = (u32)t;
            base += (u32)__popcll(m);
        }
        if (tid == 0) { s_nseg = base; s_start[base] = 256u; }
    }

    // layer 2: MFMA, write result back in place (swizzled 8B chunks)
    const int l = tid & 63;
    const int wbase = tid & 192;
    const int lrow = l & 15;
    const int lhi = l >> 4;

    f16x8 afrag[4][2];
#pragma unroll
    for (int at = 0; at < 4; ++at)
#pragma unroll
        for (int kt = 0; kt < 2; ++kt)
            afrag[at][kt] = *(const f16x8*)(w2t + ((at * 16 + lrow) << 6) + kt * 32 + (lhi << 3));

    f32x4 bias[4];
#pragma unroll
    for (int at = 0; at < 4; ++at)
        bias[at] = *(const f32x4*)(fb2 + at * 16 + (lhi << 2));

#pragma unroll
    for (int g = 0; g < 4; ++g) {
        const int rb = wbase + g * 16 + lrow;    // edge row within block
        f32x4 acc[4];
#pragma unroll
        for (int at = 0; at < 4; ++at) acc[at] = bias[at];
#pragma unroll
        for (int kt = 0; kt < 2; ++kt) {
            const int sc = (kt * 4 + lhi) ^ (rb & 7);
            f16x8 b = *(const f16x8*)&s_h[(rb << 6) + (sc << 3)];
            acc[0] = __builtin_amdgcn_mfma_f32_16x16x32_f16(afrag[0][kt], b, acc[0], 0, 0, 0);
            acc[1] = __builtin_amdgcn_mfma_f32_16x16x32_f16(afrag[1][kt], b, acc[1], 0, 0, 0);
            acc[2] = __builtin_amdgcn_mfma_f32_16x16x32_f16(afrag[2][kt], b, acc[2], 0, 0, 0);
            acc[3] = __builtin_amdgcn_mfma_f32_16x16x32_f16(afrag[3][kt], b, acc[3], 0, 0, 0);
        }
#pragma unroll
        for (int at = 0; at < 4; ++at) {
            const int c8b = (at * 4 + lhi) ^ (rb & 15);   // 8B-chunk index, swizzled
            union { uint2 u; __half2 h2[2]; } pk;
            pk.h2[0] = __floats2half2_rn(acc[at][0], acc[at][1]);
            pk.h2[1] = __floats2half2_rn(acc[at][2], acc[at][3]);
            *(uint2*)&s_h[(rb << 6) + (c8b << 2)] = pk.u;
        }
    }
    __syncthreads();   // messages + segment table ready

    // segmented max-reduce: half-wave per segment, lane = half2 channel
    const int hw = tid >> 5;
    const int lane2 = tid & 31;
    const u32 nseg = s_nseg;
    for (u32 j = (u32)hw; j < nseg; j += 8) {
        const u32 lo = s_start[j];
        const u32 hi = s_start[j + 1];
        const u32 node = s_d[lo];
        float2 m = make_float2(0.f, 0.f);
        for (u32 r = lo; r < hi; ++r) {
            const u32 c8b = ((u32)(lane2 >> 1)) ^ (r & 15u);
            __half2 hv = *(const __half2*)&s_h[(r << 6) + (c8b << 2) + ((lane2 & 1) << 1)];
            float2 f = __half22float2(hv);
            m.x = fmaxf(m.x, f.x);
            m.y = fmaxf(m.y, f.y);
        }
        u32* arow = aggr + (size_t)node * 64 + lane2 * 2;
        if (m.x > 0.f) atomicMax(&arow[0], __float_as_uint(m.x));
        if (m.y > 0.f) atomicMax(&arow[1], __float_as_uint(m.y));
    }
}

// ======================= node update MLP =======================

__global__ __launch_bounds__(256) void node_kernel(
    const float* __restrict__ x,
    float* io,   // d_out: aggr in, final out (in place, thread owns its row)
    const float* __restrict__ gw1, const float* __restrict__ gb1,
    const float* __restrict__ gw2, const float* __restrict__ gb2)
{
    __shared__ __align__(16) float s_w1[67 * 64];
    __shared__ __align__(16) float s_b1[64];
    __shared__ __align__(16) float s_w2[64 * 64];
    __shared__ __align__(16) float s_b2[64];

    const int tid = threadIdx.x;
    for (int i = tid; i < 67 * 64; i += 256) s_w1[i] = gw1[i];
    for (int i = tid; i < 64 * 64; i += 256) s_w2[i] = gw2[i];
    if (tid < 64) { s_b1[tid] = gb1[tid]; s_b2[tid] = gb2[tid]; }
    __syncthreads();

    const int n = blockIdx.x * 256 + tid;
    if (n >= NN) return;

    float a[64];
#pragma unroll
    for (int k = 0; k < 64; k += 4) {
        float4 v = *(const float4*)&io[(size_t)n * 64 + k];
        a[k + 0] = v.x; a[k + 1] = v.y; a[k + 2] = v.z; a[k + 3] = v.w;
    }
    float xv[3];
    xv[0] = x[n * 3 + 0];
    xv[1] = x[n * 3 + 1];
    xv[2] = x[n * 3 + 2];

    float u[64];
    for (int j = 0; j < 64; j += 4) {
        float4 acc = *(const float4*)&s_b1[j];
#pragma unroll
        for (int k = 0; k < 64; ++k) {
            float4 w = *(const float4*)&s_w1[k * 64 + j];
            acc.x = fmaf(a[k], w.x, acc.x);
            acc.y = fmaf(a[k], w.y, acc.y);
            acc.z = fmaf(a[k], w.z, acc.z);
            acc.w = fmaf(a[k], w.w, acc.w);
        }
#pragma unroll
        for (int q = 0; q < 3; ++q) {
            float4 w = *(const float4*)&s_w1[(64 + q) * 64 + j];
            acc.x = fmaf(xv[q], w.x, acc.x);
            acc.y = fmaf(xv[q], w.y, acc.y);
            acc.z = fmaf(xv[q], w.z, acc.z);
            acc.w = fmaf(xv[q], w.w, acc.w);
        }
        u[j + 0] = celu_f(acc.x);
        u[j + 1] = celu_f(acc.y);
        u[j + 2] = celu_f(acc.z);
        u[j + 3] = celu_f(acc.w);
    }

    float* orow = &io[(size_t)n * 64];
    for (int j = 0; j < 64; j += 4) {
        float4 acc = *(const float4*)&s_b2[j];
#pragma unroll
        for (int k = 0; k < 64; ++k) {
            float4 w = *(const float4*)&s_w2[k * 64 + j];
            acc.x = fmaf(u[k], w.x, acc.x);
            acc.y = fmaf(u[k], w.y, acc.y);
            acc.z = fmaf(u[k], w.z, acc.z);
            acc.w = fmaf(u[k], w.w, acc.w);
        }
        float4 r;
        r.x = celu_f(acc.x);
        r.y = celu_f(acc.y);
        r.z = celu_f(acc.z);
        r.w = celu_f(acc.w);
        *(float4*)&orow[j] = r;
    }
}

// ======================= fallback (atomic path) =======================

__global__ __launch_bounds__(256) void zero_kernel(float4* __restrict__ p, int n4) {
    int i = blockIdx.x * blockDim.x + threadIdx.x;
    if (i < n4) p[i] = make_float4(0.f, 0.f, 0.f, 0.f);
}

__global__ __launch_bounds__(256) void edge_atomic_kernel(
    const float* __restrict__ x, const float* __restrict__ pos,
    const int* __restrict__ ei,
    const float* __restrict__ fw1, const float* __restrict__ fb1,
    const float* __restrict__ fw2, const float* __restrict__ fb2,
    unsigned int* __restrict__ aggr)
{
    __shared__ __align__(16) float s_w1[6 * 64];
    __shared__ __align__(16) float s_b1[64];
    __shared__ __align__(16) float s_w2[64 * 64];
    __shared__ __align__(16) float s_b2[64];

    const int tid = threadIdx.x;
    for (int i = tid; i < 6 * 64; i += 256) s_w1[i] = fw1[i];
    for (int i = tid; i < 64 * 64; i += 256) s_w2[i] = fw2[i];
    if (tid < 64) { s_b1[tid] = fb1[tid]; s_b2[tid] = fb2[tid]; }
    __syncthreads();

    const int e = blockIdx.x * 256 + tid;
    if (e >= NE) return;

    const int s = ei[e];
    const int d = ei[NE + e];

    float in[6];
    in[0] = x[s * 3 + 0];
    in[1] = x[s * 3 + 1];
    in[2] = x[s * 3 + 2];
    in[3] = pos[s * 3 + 0] - pos[d * 3 + 0];
    in[4] = pos[s * 3 + 1] - pos[d * 3 + 1];
    in[5] = pos[s * 3 + 2] - pos[d * 3 + 2];

    float h[64];
#pragma unroll
    for (int k = 0; k < 64; k += 4) {
        float4 acc = *(const float4*)&s_b1[k];
#pragma unroll
        for (int q = 0; q < 6; ++q) {
            float4 w = *(const float4*)&s_w1[q * 64 + k];
            acc.x = fmaf(in[q], w.x, acc.x);
            acc.y = fmaf(in[q], w.y, acc.y);
            acc.z = fmaf(in[q], w.z, acc.z);
            acc.w = fmaf(in[q], w.w, acc.w);
        }
        h[k + 0] = celu_f(acc.x);
        h[k + 1] = celu_f(acc.y);
        h[k + 2] = celu_f(acc.z);
        h[k + 3] = celu_f(acc.w);
    }

    unsigned int* arow = aggr + (size_t)d * 64;
    for (int o = 0; o < 64; o += 4) {
        float4 acc = *(const float4*)&s_b2[o];
#pragma unroll
        for (int k = 0; k < 64; ++k) {
            float4 w = *(const float4*)&s_w2[k * 64 + o];
            acc.x = fmaf(h[k], w.x, acc.x);
            acc.y = fmaf(h[k], w.y, acc.y);
            acc.z = fmaf(h[k], w.z, acc.z);
            acc.w = fmaf(h[k], w.w, acc.w);
        }
        if (acc.x > 0.f) atomicMax(&arow[o + 0], __float_as_uint(acc.x));
        if (acc.y > 0.f) atomicMax(&arow[o + 1], __float_as_uint(acc.y));
        if (acc.z > 0.f) atomicMax(&arow[o + 2], __float_as_uint(acc.z));
        if (acc.w > 0.f) atomicMax(&arow[o + 3], __float_as_uint(acc.w));
    }
}

// ======================= launcher =======================

extern "C" void kernel_launch(void* const* d_in, const int* in_sizes, int n_in,
                              void* d_out, int out_size, void* d_ws, size_t ws_size,
                              hipStream_t stream) {
    const float* x   = (const float*)d_in[0];
    const float* pos = (const float*)d_in[1];
    const int*   ei  = (const int*)d_in[2];
    const float* fw1 = (const float*)d_in[3];
    const float* fb1 = (const float*)d_in[4];
    const float* fw2 = (const float*)d_in[5];
    const float* fb2 = (const float*)d_in[6];
    const float* gw1 = (const float*)d_in[7];
    const float* gb1 = (const float*)d_in[8];
    const float* gw2 = (const float*)d_in[9];
    const float* gb2 = (const float*)d_in[10];
    float* out = (float*)d_out;

    const int n4 = NN * 64 / 4;
    const int NBE = (NE + 4095) / 4096;   // 391 binning blocks

    auto al = [](size_t v) { return (v + 255) & ~(size_t)255; };
    const size_t o_gcnt = 0;
    const size_t o_gbas = al(o_gcnt + (size_t)NBKT * 4);
    const size_t o_gcur = al(o_gbas + (size_t)(NBKT + 1) * 4);
    const size_t o_w2t  = al(o_gcur + (size_t)NBKT * 4);
    const size_t o_sd1  = al(o_w2t + (size_t)64 * 64 * 2);
    const size_t o_sd2  = al(o_sd1 + (size_t)NE * 8);
    const size_t need   = o_sd2 + (size_t)NE * 8;

    if (ws_size >= need) {
        char* w = (char*)d_ws;
        u32*    gcnt = (u32*)(w + o_gcnt);
        u32*    gbas = (u32*)(w + o_gbas);
        u32*    gcur = (u32*)(w + o_gcur);
        __half* w2t  = (__half*)(w + o_w2t);
        u64*    sd1  = (u64*)(w + o_sd1);
        u64*    sd2  = (u64*)(w + o_sd2);

        hipMemsetAsync(out, 0, (size_t)NN * 64 * 4, stream);
        hipMemsetAsync(gcnt, 0, (size_t)NBKT * 4, stream);
        prep_w2t_kernel<<<16, 256, 0, stream>>>(fw2, w2t);
        hist_bkt_kernel<<<NBE, 256, 0, stream>>>(ei, gcnt);
        scan_bkt_kernel<<<1, 128, 0, stream>>>(gcnt, gbas, gcur);
        binA_kernel<<<NBE, 256, 0, stream>>>(ei, gcur, sd1);
        sortB_kernel<<<NBKT, 256, 0, stream>>>(sd1, gbas, sd2);
        edge_fused_kernel<<<NE / 256, 256, 0, stream>>>(x, pos, sd2, fw1, fb1,
                                                        w2t, fb2, (u32*)out);
        node_kernel<<<(NN + 255) / 256, 256, 0, stream>>>(x, out, gw1, gb1, gw2, gb2);
    } else {
        // fallback: atomic path (ws too small)
        zero_kernel<<<(n4 + 255) / 256, 256, 0, stream>>>((float4*)out, n4);
        edge_atomic_kernel<<<NE / 256, 256, 0, stream>>>(x, pos, ei, fw1, fb1,
                                                         fw2, fb2, (unsigned int*)out);
        node_kernel<<<(NN + 255) / 256, 256, 0, stream>>>(x, out, gw1, gb1, gw2, gb2);
    }
}

// Round 8
// 192.331 us; speedup vs baseline: 2.5922x; 1.4100x over previous
//
#include <hip/hip_runtime.h>
#include <hip/hip_fp16.h>
#include <math.h>

#define NN 50000
#define NE 1600000
#define NBKT 98          // ceil(50000 / 512)
#define BKT_SHIFT 9      // 512 nodes per bucket

typedef unsigned int u32;
typedef unsigned long long u64;
typedef _Float16 f16x8 __attribute__((ext_vector_type(8)));
typedef float f32x4 __attribute__((ext_vector_type(4)));

// fast celu: __expf is the HW v_exp path; abs err ~1e-7, threshold is 1.97e-2
__device__ __forceinline__ float celu_fast(float v) {
    return v > 0.0f ? v : __expf(v) - 1.0f;
}

// unified swizzled LDS layout for the h/msg tile: 8B chunks (4 f16),
// chunk c4 of row r lives at half-index r*64 + (c4 ^ ((r&7)<<1))*4.
// XOR value is even -> 16B pairs {2c8, 2c8+1} stay contiguous.
__device__ __forceinline__ __half* hptr(__half* base, int row, int c4) {
    return base + (row << 6) + ((c4 ^ ((row & 7) << 1)) << 2);
}

// ======================= bucketed counting sort =======================

__global__ __launch_bounds__(256) void hist_bkt_kernel(const int* __restrict__ ei,
                                                       u32* __restrict__ gcnt) {
    __shared__ u32 s_h[NBKT];
    const int tid = threadIdx.x;
    if (tid < NBKT) s_h[tid] = 0u;
    __syncthreads();
    const int e0 = blockIdx.x * 4096 + tid * 16;
    if (e0 < NE) {
        const int4* dp = (const int4*)&ei[NE + e0];
#pragma unroll
        for (int q = 0; q < 4; ++q) {
            int4 d4 = dp[q];
            atomicAdd(&s_h[d4.x >> BKT_SHIFT], 1u);
            atomicAdd(&s_h[d4.y >> BKT_SHIFT], 1u);
            atomicAdd(&s_h[d4.z >> BKT_SHIFT], 1u);
            atomicAdd(&s_h[d4.w >> BKT_SHIFT], 1u);
        }
    }
    __syncthreads();
    if (tid < NBKT && s_h[tid]) atomicAdd(&gcnt[tid], s_h[tid]);
}

__global__ __launch_bounds__(128) void scan_bkt_kernel(const u32* __restrict__ gcnt,
                                                       u32* __restrict__ gbase,
                                                       u32* __restrict__ gcur) {
    __shared__ u32 s[128];
    const int tid = threadIdx.x;
    u32 v = (tid < NBKT) ? gcnt[tid] : 0u;
    s[tid] = v;
    __syncthreads();
    for (int d = 1; d < 128; d <<= 1) {
        u32 t = (tid >= d) ? s[tid - d] : 0u;
        __syncthreads();
        s[tid] += t;
        __syncthreads();
    }
    if (tid < NBKT) {
        gbase[tid + 1] = s[tid];
        gcur[tid] = s[tid] - v;
    }
    if (tid == 0) gbase[0] = 0u;
}

__global__ __launch_bounds__(256) void binA_kernel(const int* __restrict__ ei,
                                                   u32* __restrict__ gcur,
                                                   u64* __restrict__ sd1) {
    __shared__ u32 s_hist[NBKT];
    __shared__ u32 s_base[NBKT];
    __shared__ u32 s_cur[NBKT];
    const int tid = threadIdx.x;
    if (tid < NBKT) { s_hist[tid] = 0u; s_cur[tid] = 0u; }
    __syncthreads();

    const int e0 = blockIdx.x * 4096 + tid * 16;
    const bool valid = (e0 < NE);
    u64 ed[16];
    if (valid) {
        const int4* sp = (const int4*)&ei[e0];
        const int4* dp = (const int4*)&ei[NE + e0];
#pragma unroll
        for (int q = 0; q < 4; ++q) {
            int4 s4 = sp[q];
            int4 d4 = dp[q];
            ed[q * 4 + 0] = (u32)s4.x | ((u64)(u32)d4.x << 32);
            ed[q * 4 + 1] = (u32)s4.y | ((u64)(u32)d4.y << 32);
            ed[q * 4 + 2] = (u32)s4.z | ((u64)(u32)d4.z << 32);
            ed[q * 4 + 3] = (u32)s4.w | ((u64)(u32)d4.w << 32);
        }
#pragma unroll
        for (int q = 0; q < 16; ++q)
            atomicAdd(&s_hist[(u32)(ed[q] >> 32) >> BKT_SHIFT], 1u);
    }
    __syncthreads();
    if (tid < NBKT && s_hist[tid]) s_base[tid] = atomicAdd(&gcur[tid], s_hist[tid]);
    __syncthreads();
    if (valid) {
#pragma unroll
        for (int q = 0; q < 16; ++q) {
            const u32 b = (u32)(ed[q] >> 32) >> BKT_SHIFT;
            const u32 r = atomicAdd(&s_cur[b], 1u);
            sd1[s_base[b] + r] = ed[q];
        }
    }
}

__global__ __launch_bounds__(256) void sortB_kernel(const u64* __restrict__ sd1,
                                                    const u32* __restrict__ gbase,
                                                    u64* __restrict__ sd2) {
    __shared__ u32 s_cnt[512];
    __shared__ u32 s_scan[512];
    const int tid = threadIdx.x;
    const u32 lo = gbase[blockIdx.x];
    const u32 hi = gbase[blockIdx.x + 1];

    s_cnt[tid] = 0u; s_cnt[tid + 256] = 0u;
    __syncthreads();
    for (u32 j = lo + tid; j < hi; j += 256)
        atomicAdd(&s_cnt[(u32)(sd1[j] >> 32) & 511u], 1u);
    __syncthreads();
    s_scan[tid] = s_cnt[tid];
    s_scan[tid + 256] = s_cnt[tid + 256];
    __syncthreads();
    for (int d = 1; d < 512; d <<= 1) {
        const int i0 = tid, i1 = tid + 256;
        u32 a0 = (i0 >= d) ? s_scan[i0 - d] : 0u;
        u32 a1 = (i1 >= d) ? s_scan[i1 - d] : 0u;
        __syncthreads();
        s_scan[i0] += a0;
        s_scan[i1] += a1;
        __syncthreads();
    }
    s_scan[tid] -= s_cnt[tid];
    s_scan[tid + 256] -= s_cnt[tid + 256];
    __syncthreads();
    for (u32 j = lo + tid; j < hi; j += 256) {
        const u64 sd = sd1[j];
        const u32 dl = (u32)(sd >> 32) & 511u;
        const u32 r = atomicAdd(&s_scan[dl], 1u);
        sd2[lo + r] = sd;
    }
}

// ======================= weight prep =======================

// w2t[n*64+k] = fw2[k][n] f16;  w1t[n*8+k] = fw1[k][n] f16 (k>=6 -> 0)
__global__ __launch_bounds__(256) void prep_w_kernel(const float* __restrict__ fw1,
                                                     const float* __restrict__ fw2,
                                                     __half* __restrict__ w1t,
                                                     __half* __restrict__ w2t) {
    int i = blockIdx.x * 256 + threadIdx.x;   // 4608 total
    if (i < 4096) {
        int n = i >> 6, k = i & 63;
        w2t[n * 64 + k] = __float2half(fw2[k * 64 + n]);
    } else if (i < 4608) {
        int j = i - 4096;
        int n = j >> 3, k = j & 7;
        w1t[j] = (k < 6) ? __float2half(fw1[k * 64 + n]) : __half(0.0f);
    }
}

// ======================= fused edge+gather kernel =======================
//
// One thread per SORTED edge slot; 256 edges per block, 4 waves.
// Phase 0: gather x/pos, cvt f16, stage in[8] (k-padded) to s_in.
// Phase 1 (L1, MFMA): z[64ch][256e] = w1t[64][8k] @ s_in^T; K=32 MFMA with
//   hi>0 lanes supplying zero fragments (k>=8 == 0). D: col=edge, row=ch.
//   celu_fast + cvt f16, write 8B chunks into swizzled s_h.
// Phase 2 (L2, MFMA): msg = W2^T @ h from s_h, written back in place.
// Phase 3: per-block segmented max-reduce over sorted dst runs,
//   one atomicMax per (node,ch,block) into zero-init'd aggr (= relu + max).
__global__ __launch_bounds__(256, 4) void edge_fused_kernel(
    const float* __restrict__ x, const float* __restrict__ pos,
    const u64* __restrict__ sdb,
    const __half* __restrict__ w1t, const float* __restrict__ fb1,
    const __half* __restrict__ w2t, const float* __restrict__ fb2,
    u32* __restrict__ aggr)
{
    __shared__ __align__(16) __half s_in[256 * 8];   // 4 KiB
    __shared__ __align__(16) __half s_h[256 * 64];   // 32 KiB, swizzled
    __shared__ u32 s_d[256];
    __shared__ u32 s_start[257];
    __shared__ u32 s_nseg;

    const int tid = threadIdx.x;
    const int i = blockIdx.x * 256 + tid;   // NE % 256 == 0
    const u64 sd = sdb[i];
    const int s = (int)(u32)sd;
    const int d = (int)(u32)(sd >> 32);
    s_d[tid] = (u32)d;

    {
        float i0 = x[s * 3 + 0];
        float i1 = x[s * 3 + 1];
        float i2 = x[s * 3 + 2];
        float i3 = pos[s * 3 + 0] - pos[d * 3 + 0];
        float i4 = pos[s * 3 + 1] - pos[d * 3 + 1];
        float i5 = pos[s * 3 + 2] - pos[d * 3 + 2];
        union { uint4 u; __half2 h2[4]; } pk;
        pk.h2[0] = __floats2half2_rn(i0, i1);
        pk.h2[1] = __floats2half2_rn(i2, i3);
        pk.h2[2] = __floats2half2_rn(i4, i5);
        pk.h2[3] = __floats2half2_rn(0.f, 0.f);
        *(uint4*)&s_in[tid * 8] = pk.u;
    }
    __syncthreads();   // s_in + s_d ready

    const int l = tid & 63;
    const int wbase = tid & 192;   // wave's 64-edge base row
    const int lrow = l & 15;
    const int lhi = l >> 4;

    // ---- layer 1 on MFMA ----
    const f16x8 zero8 = {};
    f16x8 b1f[4];
#pragma unroll
    for (int nt = 0; nt < 4; ++nt) {
        b1f[nt] = zero8;
        if (lhi == 0)
            b1f[nt] = *(const f16x8*)&s_in[(wbase + nt * 16 + lrow) * 8];
    }

#pragma unroll
    for (int mt = 0; mt < 4; ++mt) {
        f16x8 a = zero8;
        if (lhi == 0) a = *(const f16x8*)&w1t[(mt * 16 + lrow) * 8];
        const f32x4 c0 = *(const f32x4*)&fb1[mt * 16 + lhi * 4];
#pragma unroll
        for (int nt = 0; nt < 4; ++nt) {
            f32x4 z = __builtin_amdgcn_mfma_f32_16x16x32_f16(a, b1f[nt], c0, 0, 0, 0);
            const int row = wbase + nt * 16 + lrow;
            union { uint2 u; __half2 h2[2]; } pk;
            pk.h2[0] = __floats2half2_rn(celu_fast(z[0]), celu_fast(z[1]));
            pk.h2[1] = __floats2half2_rn(celu_fast(z[2]), celu_fast(z[3]));
            *(uint2*)hptr(s_h, row, mt * 4 + lhi) = pk.u;
        }
    }

    // wave 0: segment head-scan over sorted dst -> s_start[0..nseg]
    if (tid < 64) {
        u32 base = 0;
        for (int c = 0; c < 4; ++c) {
            const int t = c * 64 + tid;
            const bool head = (t == 0) || (s_d[t] != s_d[t - 1]);
            const u64 m = __ballot(head);
            const u32 pos0 = base + (u32)__popcll(m & ((1ull << tid) - 1ull));
            if (head) s_start[pos0] = (u32)t;
            base += (u32)__popcll(m);
        }
        if (tid == 0) { s_nseg = base; s_start[base] = 256u; }
    }

    // L2 weight fragments + bias (global, L2-cached)
    f16x8 afrag[4][2];
#pragma unroll
    for (int at = 0; at < 4; ++at)
#pragma unroll
        for (int kt = 0; kt < 2; ++kt)
            afrag[at][kt] = *(const f16x8*)(w2t + ((at * 16 + lrow) << 6) + kt * 32 + (lhi << 3));
    f32x4 bias2[4];
#pragma unroll
    for (int at = 0; at < 4; ++at)
        bias2[at] = *(const f32x4*)(fb2 + at * 16 + (lhi << 2));

    __syncthreads();   // s_h (h values) ready

    // ---- layer 2 on MFMA, in-place writeback ----
#pragma unroll
    for (int g = 0; g < 4; ++g) {
        const int rb = wbase + g * 16 + lrow;
        f32x4 acc[4];
#pragma unroll
        for (int at = 0; at < 4; ++at) acc[at] = bias2[at];
#pragma unroll
        for (int kt = 0; kt < 2; ++kt) {
            f16x8 b = *(const f16x8*)hptr(s_h, rb, (kt * 4 + lhi) * 2);
            acc[0] = __builtin_amdgcn_mfma_f32_16x16x32_f16(afrag[0][kt], b, acc[0], 0, 0, 0);
            acc[1] = __builtin_amdgcn_mfma_f32_16x16x32_f16(afrag[1][kt], b, acc[1], 0, 0, 0);
            acc[2] = __builtin_amdgcn_mfma_f32_16x16x32_f16(afrag[2][kt], b, acc[2], 0, 0, 0);
            acc[3] = __builtin_amdgcn_mfma_f32_16x16x32_f16(afrag[3][kt], b, acc[3], 0, 0, 0);
        }
#pragma unroll
        for (int at = 0; at < 4; ++at) {
            union { uint2 u; __half2 h2[2]; } pk;
            pk.h2[0] = __floats2half2_rn(acc[at][0], acc[at][1]);
            pk.h2[1] = __floats2half2_rn(acc[at][2], acc[at][3]);
            *(uint2*)hptr(s_h, rb, at * 4 + lhi) = pk.u;
        }
    }
    __syncthreads();   // messages + segment table ready

    // ---- segmented max-reduce: half-wave per segment, f32 max ----
    const int hw = tid >> 5;
    const int lane2 = tid & 31;
    const u32 nseg = s_nseg;
    for (u32 j = (u32)hw; j < nseg; j += 8) {
        const u32 lo = s_start[j];
        const u32 hi = s_start[j + 1];
        const u32 node = s_d[lo];
        float2 m = make_float2(0.f, 0.f);
        for (u32 r = lo; r < hi; ++r) {
            __half2 v = *((const __half2*)hptr(s_h, (int)r, lane2 >> 1) + (lane2 & 1));
            float2 f = __half22float2(v);
            m.x = fmaxf(m.x, f.x);
            m.y = fmaxf(m.y, f.y);
        }
        u32* arow = aggr + (size_t)node * 64 + lane2 * 2;
        if (m.x > 0.f) atomicMax(&arow[0], __float_as_uint(m.x));
        if (m.y > 0.f) atomicMax(&arow[1], __float_as_uint(m.y));
    }
}

// ======================= node update MLP =======================

__global__ __launch_bounds__(256) void node_kernel(
    const float* __restrict__ x,
    float* io,   // d_out: aggr in, final out (in place, thread owns its row)
    const float* __restrict__ gw1, const float* __restrict__ gb1,
    const float* __restrict__ gw2, const float* __restrict__ gb2)
{
    __shared__ __align__(16) float s_w1[67 * 64];
    __shared__ __align__(16) float s_b1[64];
    __shared__ __align__(16) float s_w2[64 * 64];
    __shared__ __align__(16) float s_b2[64];

    const int tid = threadIdx.x;
    for (int i = tid; i < 67 * 64; i += 256) s_w1[i] = gw1[i];
    for (int i = tid; i < 64 * 64; i += 256) s_w2[i] = gw2[i];
    if (tid < 64) { s_b1[tid] = gb1[tid]; s_b2[tid] = gb2[tid]; }
    __syncthreads();

    const int n = blockIdx.x * 256 + tid;
    if (n >= NN) return;

    float a[64];
#pragma unroll
    for (int k = 0; k < 64; k += 4) {
        float4 v = *(const float4*)&io[(size_t)n * 64 + k];
        a[k + 0] = v.x; a[k + 1] = v.y; a[k + 2] = v.z; a[k + 3] = v.w;
    }
    float xv[3];
    xv[0] = x[n * 3 + 0];
    xv[1] = x[n * 3 + 1];
    xv[2] = x[n * 3 + 2];

    float u[64];
    for (int j = 0; j < 64; j += 4) {
        float4 acc = *(const float4*)&s_b1[j];
#pragma unroll
        for (int k = 0; k < 64; ++k) {
            float4 w = *(const float4*)&s_w1[k * 64 + j];
            acc.x = fmaf(a[k], w.x, acc.x);
            acc.y = fmaf(a[k], w.y, acc.y);
            acc.z = fmaf(a[k], w.z, acc.z);
            acc.w = fmaf(a[k], w.w, acc.w);
        }
#pragma unroll
        for (int q = 0; q < 3; ++q) {
            float4 w = *(const float4*)&s_w1[(64 + q) * 64 + j];
            acc.x = fmaf(xv[q], w.x, acc.x);
            acc.y = fmaf(xv[q], w.y, acc.y);
            acc.z = fmaf(xv[q], w.z, acc.z);
            acc.w = fmaf(xv[q], w.w, acc.w);
        }
        u[j + 0] = celu_fast(acc.x);
        u[j + 1] = celu_fast(acc.y);
        u[j + 2] = celu_fast(acc.z);
        u[j + 3] = celu_fast(acc.w);
    }

    float* orow = &io[(size_t)n * 64];
    for (int j = 0; j < 64; j += 4) {
        float4 acc = *(const float4*)&s_b2[j];
#pragma unroll
        for (int k = 0; k < 64; ++k) {
            float4 w = *(const float4*)&s_w2[k * 64 + j];
            acc.x = fmaf(u[k], w.x, acc.x);
            acc.y = fmaf(u[k], w.y, acc.y);
            acc.z = fmaf(u[k], w.z, acc.z);
            acc.w = fmaf(u[k], w.w, acc.w);
        }
        float4 r;
        r.x = celu_fast(acc.x);
        r.y = celu_fast(acc.y);
        r.z = celu_fast(acc.z);
        r.w = celu_fast(acc.w);
        *(float4*)&orow[j] = r;
    }
}

// ======================= fallback (atomic path) =======================

__global__ __launch_bounds__(256) void zero_kernel(float4* __restrict__ p, int n4) {
    int i = blockIdx.x * blockDim.x + threadIdx.x;
    if (i < n4) p[i] = make_float4(0.f, 0.f, 0.f, 0.f);
}

__global__ __launch_bounds__(256) void edge_atomic_kernel(
    const float* __restrict__ x, const float* __restrict__ pos,
    const int* __restrict__ ei,
    const float* __restrict__ fw1, const float* __restrict__ fb1,
    const float* __restrict__ fw2, const float* __restrict__ fb2,
    unsigned int* __restrict__ aggr)
{
    __shared__ __align__(16) float s_w1[6 * 64];
    __shared__ __align__(16) float s_b1[64];
    __shared__ __align__(16) float s_w2[64 * 64];
    __shared__ __align__(16) float s_b2[64];

    const int tid = threadIdx.x;
    for (int i = tid; i < 6 * 64; i += 256) s_w1[i] = fw1[i];
    for (int i = tid; i < 64 * 64; i += 256) s_w2[i] = fw2[i];
    if (tid < 64) { s_b1[tid] = fb1[tid]; s_b2[tid] = fb2[tid]; }
    __syncthreads();

    const int e = blockIdx.x * 256 + tid;
    if (e >= NE) return;

    const int s = ei[e];
    const int d = ei[NE + e];

    float in[6];
    in[0] = x[s * 3 + 0];
    in[1] = x[s * 3 + 1];
    in[2] = x[s * 3 + 2];
    in[3] = pos[s * 3 + 0] - pos[d * 3 + 0];
    in[4] = pos[s * 3 + 1] - pos[d * 3 + 1];
    in[5] = pos[s * 3 + 2] - pos[d * 3 + 2];

    float h[64];
#pragma unroll
    for (int k = 0; k < 64; k += 4) {
        float4 acc = *(const float4*)&s_b1[k];
#pragma unroll
        for (int q = 0; q < 6; ++q) {
            float4 w = *(const float4*)&s_w1[q * 64 + k];
            acc.x = fmaf(in[q], w.x, acc.x);
            acc.y = fmaf(in[q], w.y, acc.y);
            acc.z = fmaf(in[q], w.z, acc.z);
            acc.w = fmaf(in[q], w.w, acc.w);
        }
        h[k + 0] = celu_fast(acc.x);
        h[k + 1] = celu_fast(acc.y);
        h[k + 2] = celu_fast(acc.z);
        h[k + 3] = celu_fast(acc.w);
    }

    unsigned int* arow = aggr + (size_t)d * 64;
    for (int o = 0; o < 64; o += 4) {
        float4 acc = *(const float4*)&s_b2[o];
#pragma unroll
        for (int k = 0; k < 64; ++k) {
            float4 w = *(const float4*)&s_w2[k * 64 + o];
            acc.x = fmaf(h[k], w.x, acc.x);
            acc.y = fmaf(h[k], w.y, acc.y);
            acc.z = fmaf(h[k], w.z, acc.z);
            acc.w = fmaf(h[k], w.w, acc.w);
        }
        if (acc.x > 0.f) atomicMax(&arow[o + 0], __float_as_uint(acc.x));
        if (acc.y > 0.f) atomicMax(&arow[o + 1], __float_as_uint(acc.y));
        if (acc.z > 0.f) atomicMax(&arow[o + 2], __float_as_uint(acc.z));
        if (acc.w > 0.f) atomicMax(&arow[o + 3], __float_as_uint(acc.w));
    }
}

// ======================= launcher =======================

extern "C" void kernel_launch(void* const* d_in, const int* in_sizes, int n_in,
                              void* d_out, int out_size, void* d_ws, size_t ws_size,
                              hipStream_t stream) {
    const float* x   = (const float*)d_in[0];
    const float* pos = (const float*)d_in[1];
    const int*   ei  = (const int*)d_in[2];
    const float* fw1 = (const float*)d_in[3];
    const float* fb1 = (const float*)d_in[4];
    const float* fw2 = (const float*)d_in[5];
    const float* fb2 = (const float*)d_in[6];
    const float* gw1 = (const float*)d_in[7];
    const float* gb1 = (const float*)d_in[8];
    const float* gw2 = (const float*)d_in[9];
    const float* gb2 = (const float*)d_in[10];
    float* out = (float*)d_out;

    const int n4 = NN * 64 / 4;
    const int NBE = (NE + 4095) / 4096;   // 391 binning blocks

    auto al = [](size_t v) { return (v + 255) & ~(size_t)255; };
    const size_t o_gcnt = 0;
    const size_t o_gbas = al(o_gcnt + (size_t)NBKT * 4);
    const size_t o_gcur = al(o_gbas + (size_t)(NBKT + 1) * 4);
    const size_t o_w1t  = al(o_gcur + (size_t)NBKT * 4);
    const size_t o_w2t  = al(o_w1t + (size_t)64 * 8 * 2);
    const size_t o_sd1  = al(o_w2t + (size_t)64 * 64 * 2);
    const size_t o_sd2  = al(o_sd1 + (size_t)NE * 8);
    const size_t need   = o_sd2 + (size_t)NE * 8;

    if (ws_size >= need) {
        char* w = (char*)d_ws;
        u32*    gcnt = (u32*)(w + o_gcnt);
        u32*    gbas = (u32*)(w + o_gbas);
        u32*    gcur = (u32*)(w + o_gcur);
        __half* w1t  = (__half*)(w + o_w1t);
        __half* w2t  = (__half*)(w + o_w2t);
        u64*    sd1  = (u64*)(w + o_sd1);
        u64*    sd2  = (u64*)(w + o_sd2);

        (void)hipMemsetAsync(out, 0, (size_t)NN * 64 * 4, stream);
        (void)hipMemsetAsync(gcnt, 0, (size_t)NBKT * 4, stream);
        prep_w_kernel<<<18, 256, 0, stream>>>(fw1, fw2, w1t, w2t);
        hist_bkt_kernel<<<NBE, 256, 0, stream>>>(ei, gcnt);
        scan_bkt_kernel<<<1, 128, 0, stream>>>(gcnt, gbas, gcur);
        binA_kernel<<<NBE, 256, 0, stream>>>(ei, gcur, sd1);
        sortB_kernel<<<NBKT, 256, 0, stream>>>(sd1, gbas, sd2);
        edge_fused_kernel<<<NE / 256, 256, 0, stream>>>(x, pos, sd2, w1t, fb1,
                                                        w2t, fb2, (u32*)out);
        node_kernel<<<(NN + 255) / 256, 256, 0, stream>>>(x, out, gw1, gb1, gw2, gb2);
    } else {
        // fallback: atomic path (ws too small)
        zero_kernel<<<(n4 + 255) / 256, 256, 0, stream>>>((float4*)out, n4);
        edge_atomic_kernel<<<NE / 256, 256, 0, stream>>>(x, pos, ei, fw1, fb1,
                                                         fw2, fb2, (unsigned int*)out);
        node_kernel<<<(NN + 255) / 256, 256, 0, stream>>>(x, out, gw1, gb1, gw2, gb2);
    }
}

// Round 10
// 168.236 us; speedup vs baseline: 2.9635x; 1.1432x over previous
//
#include <hip/hip_runtime.h>
#include <hip/hip_fp16.h>
#include <math.h>

#define NN 50000
#define NE 1600000
#define NBKT 98          // ceil(50000 / 512)
#define BKT_SHIFT 9      // 512 nodes per bucket

typedef unsigned int u32;
typedef unsigned long long u64;
typedef _Float16 f16x8 __attribute__((ext_vector_type(8)));
typedef _Float16 f16x4 __attribute__((ext_vector_type(4)));
typedef float f32x4 __attribute__((ext_vector_type(4)));

// fast celu: __expf is the HW v_exp path; abs err ~1e-7, threshold is 1.97e-2
__device__ __forceinline__ float celu_fast(float v) {
    return v > 0.0f ? v : __expf(v) - 1.0f;
}

// unified swizzled LDS layout for 128B-row f16 tiles: 8B chunks (4 f16),
// chunk c4 of row r lives at half-index r*64 + (c4 ^ ((r&7)<<1))*4.
// XOR value is even -> 16B pairs {2c8, 2c8+1} stay contiguous.
__device__ __forceinline__ __half* hptr(__half* base, int row, int c4) {
    return base + (row << 6) + ((c4 ^ ((row & 7) << 1)) << 2);
}

// ======================= init: zero aggr + zero gcnt + weight prep =======================
// blocks 0..3124: zero aggr (800000 uint4). block 3125: weight transposes + gcnt.
__global__ __launch_bounds__(256) void init_kernel(
    uint4* __restrict__ aggr4,
    const float* __restrict__ fw1, const float* __restrict__ fw2,
    const float* __restrict__ gw1, const float* __restrict__ gw2,
    __half* __restrict__ w1t, __half* __restrict__ w2t,
    __half* __restrict__ g1t, __half* __restrict__ g2t,
    float* __restrict__ w1x, u32* __restrict__ gcnt)
{
    const int tid = threadIdx.x;
    const int b = blockIdx.x;
    if (b < 3125) {
        aggr4[b * 256 + tid] = make_uint4(0u, 0u, 0u, 0u);
        return;
    }
    // weight prep block
    for (int i = tid; i < 4096; i += 256) {
        const int n = i >> 6, k = i & 63;
        w2t[i] = __float2half(fw2[k * 64 + n]);
        g1t[i] = __float2half(gw1[k * 64 + n]);   // rows 0..63 of gw1
        g2t[i] = __float2half(gw2[k * 64 + n]);
    }
    for (int j = tid; j < 512; j += 256) {        // FIX: grid-stride (was if tid<512 with 256 threads)
        const int n = j >> 3, k = j & 7;
        w1t[j] = (k < 6) ? __float2half(fw1[k * 64 + n]) : __half(0.0f);
    }
    if (tid < 192) {
        const int c = tid >> 6, ch = tid & 63;
        w1x[tid] = gw1[(64 + c) * 64 + ch];
    }
    if (tid < NBKT) gcnt[tid] = 0u;
}

// ======================= bucketed counting sort (u32-packed keys) =======================
// key = (dst<<16) | src  (both < 65536)

__global__ __launch_bounds__(256) void hist_bkt_kernel(const int* __restrict__ ei,
                                                       u32* __restrict__ gcnt) {
    __shared__ u32 s_h[NBKT];
    const int tid = threadIdx.x;
    if (tid < NBKT) s_h[tid] = 0u;
    __syncthreads();
    const int e0 = blockIdx.x * 4096 + tid * 16;
    if (e0 < NE) {
        const int4* dp = (const int4*)&ei[NE + e0];
#pragma unroll
        for (int q = 0; q < 4; ++q) {
            int4 d4 = dp[q];
            atomicAdd(&s_h[d4.x >> BKT_SHIFT], 1u);
            atomicAdd(&s_h[d4.y >> BKT_SHIFT], 1u);
            atomicAdd(&s_h[d4.z >> BKT_SHIFT], 1u);
            atomicAdd(&s_h[d4.w >> BKT_SHIFT], 1u);
        }
    }
    __syncthreads();
    if (tid < NBKT && s_h[tid]) atomicAdd(&gcnt[tid], s_h[tid]);
}

__global__ __launch_bounds__(128) void scan_bkt_kernel(const u32* __restrict__ gcnt,
                                                       u32* __restrict__ gbase,
                                                       u32* __restrict__ gcur) {
    __shared__ u32 s[128];
    const int tid = threadIdx.x;
    u32 v = (tid < NBKT) ? gcnt[tid] : 0u;
    s[tid] = v;
    __syncthreads();
    for (int d = 1; d < 128; d <<= 1) {
        u32 t = (tid >= d) ? s[tid - d] : 0u;
        __syncthreads();
        s[tid] += t;
        __syncthreads();
    }
    if (tid < NBKT) {
        gbase[tid + 1] = s[tid];
        gcur[tid] = s[tid] - v;
    }
    if (tid == 0) gbase[0] = 0u;
}

__global__ __launch_bounds__(256) void binA_kernel(const int* __restrict__ ei,
                                                   u32* __restrict__ gcur,
                                                   u32* __restrict__ sd1) {
    __shared__ u32 s_hist[NBKT];
    __shared__ u32 s_base[NBKT];
    __shared__ u32 s_cur[NBKT];
    const int tid = threadIdx.x;
    if (tid < NBKT) { s_hist[tid] = 0u; s_cur[tid] = 0u; }
    __syncthreads();

    const int e0 = blockIdx.x * 4096 + tid * 16;
    const bool valid = (e0 < NE);
    u32 ed[16];
    if (valid) {
        const int4* sp = (const int4*)&ei[e0];
        const int4* dp = (const int4*)&ei[NE + e0];
#pragma unroll
        for (int q = 0; q < 4; ++q) {
            int4 s4 = sp[q];
            int4 d4 = dp[q];
            ed[q * 4 + 0] = ((u32)d4.x << 16) | (u32)s4.x;
            ed[q * 4 + 1] = ((u32)d4.y << 16) | (u32)s4.y;
            ed[q * 4 + 2] = ((u32)d4.z << 16) | (u32)s4.z;
            ed[q * 4 + 3] = ((u32)d4.w << 16) | (u32)s4.w;
        }
#pragma unroll
        for (int q = 0; q < 16; ++q)
            atomicAdd(&s_hist[ed[q] >> (16 + BKT_SHIFT)], 1u);
    }
    __syncthreads();
    if (tid < NBKT && s_hist[tid]) s_base[tid] = atomicAdd(&gcur[tid], s_hist[tid]);
    __syncthreads();
    if (valid) {
#pragma unroll
        for (int q = 0; q < 16; ++q) {
            const u32 b = ed[q] >> (16 + BKT_SHIFT);
            const u32 r = atomicAdd(&s_cur[b], 1u);
            sd1[s_base[b] + r] = ed[q];
        }
    }
}

__global__ __launch_bounds__(256) void sortB_kernel(const u32* __restrict__ sd1,
                                                    const u32* __restrict__ gbase,
                                                    u32* __restrict__ sd2) {
    __shared__ u32 s_cnt[512];
    __shared__ u32 s_scan[512];
    const int tid = threadIdx.x;
    const u32 lo = gbase[blockIdx.x];
    const u32 hi = gbase[blockIdx.x + 1];

    s_cnt[tid] = 0u; s_cnt[tid + 256] = 0u;
    __syncthreads();
    for (u32 j = lo + tid; j < hi; j += 256)
        atomicAdd(&s_cnt[(sd1[j] >> 16) & 511u], 1u);
    __syncthreads();
    s_scan[tid] = s_cnt[tid];
    s_scan[tid + 256] = s_cnt[tid + 256];
    __syncthreads();
    for (int d = 1; d < 512; d <<= 1) {
        const int i0 = tid, i1 = tid + 256;
        u32 a0 = (i0 >= d) ? s_scan[i0 - d] : 0u;
        u32 a1 = (i1 >= d) ? s_scan[i1 - d] : 0u;
        __syncthreads();
        s_scan[i0] += a0;
        s_scan[i1] += a1;
        __syncthreads();
    }
    s_scan[tid] -= s_cnt[tid];
    s_scan[tid + 256] -= s_cnt[tid + 256];
    __syncthreads();
    for (u32 j = lo + tid; j < hi; j += 256) {
        const u32 sd = sd1[j];
        const u32 dl = (sd >> 16) & 511u;
        const u32 r = atomicAdd(&s_scan[dl], 1u);
        sd2[lo + r] = sd;
    }
}

// ======================= fused edge+gather kernel =======================
__global__ __launch_bounds__(256, 4) void edge_fused_kernel(
    const float* __restrict__ x, const float* __restrict__ pos,
    const u32* __restrict__ sdb,
    const __half* __restrict__ w1t, const float* __restrict__ fb1,
    const __half* __restrict__ w2t, const float* __restrict__ fb2,
    u32* __restrict__ aggr)
{
    __shared__ __align__(16) __half s_in[256 * 8];   // 4 KiB
    __shared__ __align__(16) __half s_h[256 * 64];   // 32 KiB, swizzled
    __shared__ u32 s_d[256];
    __shared__ u32 s_start[257];
    __shared__ u32 s_nseg;

    const int tid = threadIdx.x;
    const int i = blockIdx.x * 256 + tid;   // NE % 256 == 0
    const u32 w = sdb[i];
    const int s = (int)(w & 0xFFFFu);
    const int d = (int)(w >> 16);
    s_d[tid] = (u32)d;

    {
        float i0 = x[s * 3 + 0];
        float i1 = x[s * 3 + 1];
        float i2 = x[s * 3 + 2];
        float i3 = pos[s * 3 + 0] - pos[d * 3 + 0];
        float i4 = pos[s * 3 + 1] - pos[d * 3 + 1];
        float i5 = pos[s * 3 + 2] - pos[d * 3 + 2];
        union { uint4 u; __half2 h2[4]; } pk;
        pk.h2[0] = __floats2half2_rn(i0, i1);
        pk.h2[1] = __floats2half2_rn(i2, i3);
        pk.h2[2] = __floats2half2_rn(i4, i5);
        pk.h2[3] = __floats2half2_rn(0.f, 0.f);
        *(uint4*)&s_in[tid * 8] = pk.u;
    }
    __syncthreads();   // s_in + s_d ready

    const int l = tid & 63;
    const int wbase = tid & 192;   // wave's 64-edge base row
    const int lrow = l & 15;
    const int lhi = l >> 4;

    // ---- layer 1 on MFMA ----
    const f16x8 zero8 = {};
    f16x8 b1f[4];
#pragma unroll
    for (int nt = 0; nt < 4; ++nt) {
        b1f[nt] = zero8;
        if (lhi == 0)
            b1f[nt] = *(const f16x8*)&s_in[(wbase + nt * 16 + lrow) * 8];
    }

#pragma unroll
    for (int mt = 0; mt < 4; ++mt) {
        f16x8 a = zero8;
        if (lhi == 0) a = *(const f16x8*)&w1t[(mt * 16 + lrow) * 8];
        const f32x4 c0 = *(const f32x4*)&fb1[mt * 16 + lhi * 4];
#pragma unroll
        for (int nt = 0; nt < 4; ++nt) {
            f32x4 z = __builtin_amdgcn_mfma_f32_16x16x32_f16(a, b1f[nt], c0, 0, 0, 0);
            const int row = wbase + nt * 16 + lrow;
            union { uint2 u; __half2 h2[2]; } pk;
            pk.h2[0] = __floats2half2_rn(celu_fast(z[0]), celu_fast(z[1]));
            pk.h2[1] = __floats2half2_rn(celu_fast(z[2]), celu_fast(z[3]));
            *(uint2*)hptr(s_h, row, mt * 4 + lhi) = pk.u;
        }
    }

    // wave 0: segment head-scan over sorted dst -> s_start[0..nseg]
    if (tid < 64) {
        u32 base = 0;
        for (int c = 0; c < 4; ++c) {
            const int t = c * 64 + tid;
            const bool head = (t == 0) || (s_d[t] != s_d[t - 1]);
            const u64 m = __ballot(head);
            const u32 pos0 = base + (u32)__popcll(m & ((1ull << tid) - 1ull));
            if (head) s_start[pos0] = (u32)t;
            base += (u32)__popcll(m);
        }
        if (tid == 0) { s_nseg = base; s_start[base] = 256u; }
    }

    // L2 weight fragments + bias (global, L2-cached)
    f16x8 afrag[4][2];
#pragma unroll
    for (int at = 0; at < 4; ++at)
#pragma unroll
        for (int kt = 0; kt < 2; ++kt)
            afrag[at][kt] = *(const f16x8*)(w2t + ((at * 16 + lrow) << 6) + kt * 32 + (lhi << 3));
    f32x4 bias2[4];
#pragma unroll
    for (int at = 0; at < 4; ++at)
        bias2[at] = *(const f32x4*)(fb2 + at * 16 + (lhi << 2));

    __syncthreads();   // s_h (h values) ready

    // ---- layer 2 on MFMA, in-place writeback ----
#pragma unroll
    for (int g = 0; g < 4; ++g) {
        const int rb = wbase + g * 16 + lrow;
        f32x4 acc[4];
#pragma unroll
        for (int at = 0; at < 4; ++at) acc[at] = bias2[at];
#pragma unroll
        for (int kt = 0; kt < 2; ++kt) {
            f16x8 b = *(const f16x8*)hptr(s_h, rb, (kt * 4 + lhi) * 2);
            acc[0] = __builtin_amdgcn_mfma_f32_16x16x32_f16(afrag[0][kt], b, acc[0], 0, 0, 0);
            acc[1] = __builtin_amdgcn_mfma_f32_16x16x32_f16(afrag[1][kt], b, acc[1], 0, 0, 0);
            acc[2] = __builtin_amdgcn_mfma_f32_16x16x32_f16(afrag[2][kt], b, acc[2], 0, 0, 0);
            acc[3] = __builtin_amdgcn_mfma_f32_16x16x32_f16(afrag[3][kt], b, acc[3], 0, 0, 0);
        }
#pragma unroll
        for (int at = 0; at < 4; ++at) {
            union { uint2 u; __half2 h2[2]; } pk;
            pk.h2[0] = __floats2half2_rn(acc[at][0], acc[at][1]);
            pk.h2[1] = __floats2half2_rn(acc[at][2], acc[at][3]);
            *(uint2*)hptr(s_h, rb, at * 4 + lhi) = pk.u;
        }
    }
    __syncthreads();   // messages + segment table ready

    // ---- segmented max-reduce: half-wave per segment, 2 rows/iter, pk-max ----
    const int hw = tid >> 5;
    const int lane2 = tid & 31;
    const int sub = lane2 >> 4;      // 0: even row, 1: odd row
    const int c8 = lane2 & 15;       // logical 8B chunk -> channels c8*4..+3
    const u32 nseg = s_nseg;
    for (u32 j = (u32)hw; j < nseg; j += 8) {
        const u32 lo = s_start[j];
        const u32 hi = s_start[j + 1];
        const u32 node = s_d[lo];
        f16x4 m = {};
        for (u32 r0 = lo; r0 < hi; r0 += 2) {
            const u32 r = r0 + (u32)sub;
            if (r < hi) {
                f16x4 v = *(const f16x4*)hptr(s_h, (int)r, c8);
                m = __builtin_elementwise_max(m, v);
            }
        }
        union { f16x4 v; int w2[2]; } a, b;
        a.v = m;
        b.w2[0] = __shfl_down(a.w2[0], 16, 32);
        b.w2[1] = __shfl_down(a.w2[1], 16, 32);
        f16x4 mm = __builtin_elementwise_max(a.v, b.v);
        if (sub == 0) {
            u32* arow = aggr + (size_t)node * 64 + c8 * 4;
#pragma unroll
            for (int t = 0; t < 4; ++t) {
                float f = (float)mm[t];
                if (f > 0.f) atomicMax(&arow[t], __float_as_uint(f));
            }
        }
    }
}

// ======================= node update MLP on MFMA =======================
// 128 nodes per block (2 waves). Stage aggr f32->f16 swizzled s_a; L1 MFMA
// (A=g1t) + x-contribution via hoisted-register FMAs + celu -> s_u; L2 MFMA
// (A=g2t) + celu -> f32 out (in place over aggr; all global reads pre-sync).
__global__ __launch_bounds__(128) void node_mfma_kernel(
    const float* __restrict__ x,
    float* io,   // d_out: aggr in, final out
    const __half* __restrict__ g1t, const float* __restrict__ w1x,
    const float* __restrict__ gb1,
    const __half* __restrict__ g2t, const float* __restrict__ gb2)
{
    __shared__ __align__(16) __half s_a[128 * 64];   // 16 KiB swizzled
    __shared__ __align__(16) __half s_u[128 * 64];   // 16 KiB swizzled
    __shared__ float s_x[128 * 4];

    const int tid = threadIdx.x;
    const int n0 = blockIdx.x * 128;

    // stage aggr -> f16 swizzled (coalesced float4 reads)
#pragma unroll
    for (int it = 0; it < 16; ++it) {
        const int idx = it * 128 + tid;          // 0..2047 chunk ids
        const int row = idx >> 4, c8 = idx & 15;
        const int g = n0 + row;
        float4 v = make_float4(0.f, 0.f, 0.f, 0.f);
        if (g < NN) v = *(const float4*)&io[(size_t)g * 64 + c8 * 4];
        union { uint2 u; __half2 h2[2]; } pk;
        pk.h2[0] = __floats2half2_rn(v.x, v.y);
        pk.h2[1] = __floats2half2_rn(v.z, v.w);
        *(uint2*)hptr(s_a, row, c8) = pk.u;
    }
    // stage x
    for (int idx = tid; idx < 128 * 3; idx += 128) {
        const int row = idx / 3, c = idx - row * 3;
        const int g = n0 + row;
        s_x[row * 4 + c] = (g < NN) ? x[g * 3 + c] : 0.f;
    }
    __syncthreads();

    const int l = tid & 63;
    const int wbase = (tid >> 6) << 6;   // 0 or 64
    const int lrow = l & 15;
    const int lhi = l >> 4;

    // A-fragments and biases
    f16x8 a1[4][2], a2[4][2];
    f32x4 bias1[4], bias2[4];
    f32x4 wx0[4], wx1[4], wx2[4];   // w1x[c][ch..ch+3] per channel tile
#pragma unroll
    for (int at = 0; at < 4; ++at) {
#pragma unroll
        for (int kt = 0; kt < 2; ++kt) {
            const int off = ((at * 16 + lrow) << 6) + kt * 32 + (lhi << 3);
            a1[at][kt] = *(const f16x8*)(g1t + off);
            a2[at][kt] = *(const f16x8*)(g2t + off);
        }
        bias1[at] = *(const f32x4*)&gb1[at * 16 + lhi * 4];
        bias2[at] = *(const f32x4*)&gb2[at * 16 + lhi * 4];
        const int ch = at * 16 + lhi * 4;
        wx0[at] = *(const f32x4*)&w1x[0 * 64 + ch];
        wx1[at] = *(const f32x4*)&w1x[1 * 64 + ch];
        wx2[at] = *(const f32x4*)&w1x[2 * 64 + ch];
    }

    // ---- layer 1 ----
#pragma unroll
    for (int g = 0; g < 4; ++g) {
        const int rb = wbase + g * 16 + lrow;
        f32x4 acc[4];
#pragma unroll
        for (int at = 0; at < 4; ++at) acc[at] = bias1[at];
#pragma unroll
        for (int kt = 0; kt < 2; ++kt) {
            f16x8 b = *(const f16x8*)hptr(s_a, rb, (kt * 4 + lhi) * 2);
            acc[0] = __builtin_amdgcn_mfma_f32_16x16x32_f16(a1[0][kt], b, acc[0], 0, 0, 0);
            acc[1] = __builtin_amdgcn_mfma_f32_16x16x32_f16(a1[1][kt], b, acc[1], 0, 0, 0);
            acc[2] = __builtin_amdgcn_mfma_f32_16x16x32_f16(a1[2][kt], b, acc[2], 0, 0, 0);
            acc[3] = __builtin_amdgcn_mfma_f32_16x16x32_f16(a1[3][kt], b, acc[3], 0, 0, 0);
        }
        const float x0 = s_x[rb * 4 + 0];
        const float x1 = s_x[rb * 4 + 1];
        const float x2 = s_x[rb * 4 + 2];
#pragma unroll
        for (int at = 0; at < 4; ++at) {
            f32x4 z = acc[at];
#pragma unroll
            for (int t = 0; t < 4; ++t)
                z[t] = fmaf(x0, wx0[at][t], fmaf(x1, wx1[at][t], fmaf(x2, wx2[at][t], z[t])));
            union { uint2 u; __half2 h2[2]; } pk;
            pk.h2[0] = __floats2half2_rn(celu_fast(z[0]), celu_fast(z[1]));
            pk.h2[1] = __floats2half2_rn(celu_fast(z[2]), celu_fast(z[3]));
            *(uint2*)hptr(s_u, rb, at * 4 + lhi) = pk.u;
        }
    }
    __syncthreads();

    // ---- layer 2 + f32 celu output ----
#pragma unroll
    for (int g = 0; g < 4; ++g) {
        const int rb = wbase + g * 16 + lrow;
        const int node = n0 + rb;
        f32x4 acc[4];
#pragma unroll
        for (int at = 0; at < 4; ++at) acc[at] = bias2[at];
#pragma unroll
        for (int kt = 0; kt < 2; ++kt) {
            f16x8 b = *(const f16x8*)hptr(s_u, rb, (kt * 4 + lhi) * 2);
            acc[0] = __builtin_amdgcn_mfma_f32_16x16x32_f16(a2[0][kt], b, acc[0], 0, 0, 0);
            acc[1] = __builtin_amdgcn_mfma_f32_16x16x32_f16(a2[1][kt], b, acc[1], 0, 0, 0);
            acc[2] = __builtin_amdgcn_mfma_f32_16x16x32_f16(a2[2][kt], b, acc[2], 0, 0, 0);
            acc[3] = __builtin_amdgcn_mfma_f32_16x16x32_f16(a2[3][kt], b, acc[3], 0, 0, 0);
        }
        if (node < NN) {
#pragma unroll
            for (int at = 0; at < 4; ++at) {
                float4 r;
                r.x = celu_fast(acc[at][0]);
                r.y = celu_fast(acc[at][1]);
                r.z = celu_fast(acc[at][2]);
                r.w = celu_fast(acc[at][3]);
                *(float4*)&io[(size_t)node * 64 + at * 16 + lhi * 4] = r;
            }
        }
    }
}

// ======================= fallback (atomic path) =======================

__global__ __launch_bounds__(256) void zero_kernel(float4* __restrict__ p, int n4) {
    int i = blockIdx.x * blockDim.x + threadIdx.x;
    if (i < n4) p[i] = make_float4(0.f, 0.f, 0.f, 0.f);
}

__global__ __launch_bounds__(256) void edge_atomic_kernel(
    const float* __restrict__ x, const float* __restrict__ pos,
    const int* __restrict__ ei,
    const float* __restrict__ fw1, const float* __restrict__ fb1,
    const float* __restrict__ fw2, const float* __restrict__ fb2,
    unsigned int* __restrict__ aggr)
{
    __shared__ __align__(16) float s_w1[6 * 64];
    __shared__ __align__(16) float s_b1[64];
    __shared__ __align__(16) float s_w2[64 * 64];
    __shared__ __align__(16) float s_b2[64];

    const int tid = threadIdx.x;
    for (int i = tid; i < 6 * 64; i += 256) s_w1[i] = fw1[i];
    for (int i = tid; i < 64 * 64; i += 256) s_w2[i] = fw2[i];
    if (tid < 64) { s_b1[tid] = fb1[tid]; s_b2[tid] = fb2[tid]; }
    __syncthreads();

    const int e = blockIdx.x * 256 + tid;
    if (e >= NE) return;

    const int s = ei[e];
    const int d = ei[NE + e];

    float in[6];
    in[0] = x[s * 3 + 0];
    in[1] = x[s * 3 + 1];
    in[2] = x[s * 3 + 2];
    in[3] = pos[s * 3 + 0] - pos[d * 3 + 0];
    in[4] = pos[s * 3 + 1] - pos[d * 3 + 1];
    in[5] = pos[s * 3 + 2] - pos[d * 3 + 2];

    float h[64];
#pragma unroll
    for (int k = 0; k < 64; k += 4) {
        float4 acc = *(const float4*)&s_b1[k];
#pragma unroll
        for (int q = 0; q < 6; ++q) {
            float4 w = *(const float4*)&s_w1[q * 64 + k];
            acc.x = fmaf(in[q], w.x, acc.x);
            acc.y = fmaf(in[q], w.y, acc.y);
            acc.z = fmaf(in[q], w.z, acc.z);
            acc.w = fmaf(in[q], w.w, acc.w);
        }
        h[k + 0] = celu_fast(acc.x);
        h[k + 1] = celu_fast(acc.y);
        h[k + 2] = celu_fast(acc.z);
        h[k + 3] = celu_fast(acc.w);
    }

    unsigned int* arow = aggr + (size_t)d * 64;
    for (int o = 0; o < 64; o += 4) {
        float4 acc = *(const float4*)&s_b2[o];
#pragma unroll
        for (int k = 0; k < 64; ++k) {
            float4 w = *(const float4*)&s_w2[k * 64 + o];
            acc.x = fmaf(h[k], w.x, acc.x);
            acc.y = fmaf(h[k], w.y, acc.y);
            acc.z = fmaf(h[k], w.z, acc.z);
            acc.w = fmaf(h[k], w.w, acc.w);
        }
        if (acc.x > 0.f) atomicMax(&arow[o + 0], __float_as_uint(acc.x));
        if (acc.y > 0.f) atomicMax(&arow[o + 1], __float_as_uint(acc.y));
        if (acc.z > 0.f) atomicMax(&arow[o + 2], __float_as_uint(acc.z));
        if (acc.w > 0.f) atomicMax(&arow[o + 3], __float_as_uint(acc.w));
    }
}

__global__ __launch_bounds__(256) void node_valu_kernel(
    const float* __restrict__ x,
    float* io,
    const float* __restrict__ gw1, const float* __restrict__ gb1,
    const float* __restrict__ gw2, const float* __restrict__ gb2)
{
    __shared__ __align__(16) float s_w1[67 * 64];
    __shared__ __align__(16) float s_b1[64];
    __shared__ __align__(16) float s_w2[64 * 64];
    __shared__ __align__(16) float s_b2[64];

    const int tid = threadIdx.x;
    for (int i = tid; i < 67 * 64; i += 256) s_w1[i] = gw1[i];
    for (int i = tid; i < 64 * 64; i += 256) s_w2[i] = gw2[i];
    if (tid < 64) { s_b1[tid] = gb1[tid]; s_b2[tid] = gb2[tid]; }
    __syncthreads();

    const int n = blockIdx.x * 256 + tid;
    if (n >= NN) return;

    float a[64];
#pragma unroll
    for (int k = 0; k < 64; k += 4) {
        float4 v = *(const float4*)&io[(size_t)n * 64 + k];
        a[k + 0] = v.x; a[k + 1] = v.y; a[k + 2] = v.z; a[k + 3] = v.w;
    }
    float xv[3];
    xv[0] = x[n * 3 + 0];
    xv[1] = x[n * 3 + 1];
    xv[2] = x[n * 3 + 2];

    float u[64];
    for (int j = 0; j < 64; j += 4) {
        float4 acc = *(const float4*)&s_b1[j];
#pragma unroll
        for (int k = 0; k < 64; ++k) {
            float4 w = *(const float4*)&s_w1[k * 64 + j];
            acc.x = fmaf(a[k], w.x, acc.x);
            acc.y = fmaf(a[k], w.y, acc.y);
            acc.z = fmaf(a[k], w.z, acc.z);
            acc.w = fmaf(a[k], w.w, acc.w);
        }
#pragma unroll
        for (int q = 0; q < 3; ++q) {
            float4 w = *(const float4*)&s_w1[(64 + q) * 64 + j];
            acc.x = fmaf(xv[q], w.x, acc.x);
            acc.y = fmaf(xv[q], w.y, acc.y);
            acc.z = fmaf(xv[q], w.z, acc.z);
            acc.w = fmaf(xv[q], w.w, acc.w);
        }
        u[j + 0] = celu_fast(acc.x);
        u[j + 1] = celu_fast(acc.y);
        u[j + 2] = celu_fast(acc.z);
        u[j + 3] = celu_fast(acc.w);
    }

    float* orow = &io[(size_t)n * 64];
    for (int j = 0; j < 64; j += 4) {
        float4 acc = *(const float4*)&s_b2[j];
#pragma unroll
        for (int k = 0; k < 64; ++k) {
            float4 w = *(const float4*)&s_w2[k * 64 + j];
            acc.x = fmaf(u[k], w.x, acc.x);
            acc.y = fmaf(u[k], w.y, acc.y);
            acc.z = fmaf(u[k], w.z, acc.z);
            acc.w = fmaf(u[k], w.w, acc.w);
        }
        float4 r;
        r.x = celu_fast(acc.x);
        r.y = celu_fast(acc.y);
        r.z = celu_fast(acc.z);
        r.w = celu_fast(acc.w);
        *(float4*)&orow[j] = r;
    }
}

// ======================= launcher =======================

extern "C" void kernel_launch(void* const* d_in, const int* in_sizes, int n_in,
                              void* d_out, int out_size, void* d_ws, size_t ws_size,
                              hipStream_t stream) {
    const float* x   = (const float*)d_in[0];
    const float* pos = (const float*)d_in[1];
    const int*   ei  = (const int*)d_in[2];
    const float* fw1 = (const float*)d_in[3];
    const float* fb1 = (const float*)d_in[4];
    const float* fw2 = (const float*)d_in[5];
    const float* fb2 = (const float*)d_in[6];
    const float* gw1 = (const float*)d_in[7];
    const float* gb1 = (const float*)d_in[8];
    const float* gw2 = (const float*)d_in[9];
    const float* gb2 = (const float*)d_in[10];
    float* out = (float*)d_out;

    const int n4 = NN * 64 / 4;
    const int NBE = (NE + 4095) / 4096;   // 391 binning blocks

    auto al = [](size_t v) { return (v + 255) & ~(size_t)255; };
    const size_t o_gcnt = 0;
    const size_t o_gbas = al(o_gcnt + (size_t)NBKT * 4);
    const size_t o_gcur = al(o_gbas + (size_t)(NBKT + 1) * 4);
    const size_t o_w1t  = al(o_gcur + (size_t)NBKT * 4);
    const size_t o_w2t  = al(o_w1t + (size_t)64 * 8 * 2);
    const size_t o_g1t  = al(o_w2t + (size_t)64 * 64 * 2);
    const size_t o_g2t  = al(o_g1t + (size_t)64 * 64 * 2);
    const size_t o_w1x  = al(o_g2t + (size_t)64 * 64 * 2);
    const size_t o_sd1  = al(o_w1x + (size_t)192 * 4);
    const size_t o_sd2  = al(o_sd1 + (size_t)NE * 4);
    const size_t need   = o_sd2 + (size_t)NE * 4;

    if (ws_size >= need) {
        char* w = (char*)d_ws;
        u32*    gcnt = (u32*)(w + o_gcnt);
        u32*    gbas = (u32*)(w + o_gbas);
        u32*    gcur = (u32*)(w + o_gcur);
        __half* w1t  = (__half*)(w + o_w1t);
        __half* w2t  = (__half*)(w + o_w2t);
        __half* g1t  = (__half*)(w + o_g1t);
        __half* g2t  = (__half*)(w + o_g2t);
        float*  w1x  = (float*)(w + o_w1x);
        u32*    sd1  = (u32*)(w + o_sd1);
        u32*    sd2  = (u32*)(w + o_sd2);

        init_kernel<<<3126, 256, 0, stream>>>((uint4*)out, fw1, fw2, gw1, gw2,
                                              w1t, w2t, g1t, g2t, w1x, gcnt);
        hist_bkt_kernel<<<NBE, 256, 0, stream>>>(ei, gcnt);
        scan_bkt_kernel<<<1, 128, 0, stream>>>(gcnt, gbas, gcur);
        binA_kernel<<<NBE, 256, 0, stream>>>(ei, gcur, sd1);
        sortB_kernel<<<NBKT, 256, 0, stream>>>(sd1, gbas, sd2);
        edge_fused_kernel<<<NE / 256, 256, 0, stream>>>(x, pos, sd2, w1t, fb1,
                                                        w2t, fb2, (u32*)out);
        node_mfma_kernel<<<(NN + 127) / 128, 128, 0, stream>>>(x, out, g1t, w1x,
                                                               gb1, g2t, gb2);
    } else {
        // fallback: atomic path (ws too small)
        zero_kernel<<<(n4 + 255) / 256, 256, 0, stream>>>((float4*)out, n4);
        edge_atomic_kernel<<<NE / 256, 256, 0, stream>>>(x, pos, ei, fw1, fb1,
                                                         fw2, fb2, (unsigned int*)out);
        node_valu_kernel<<<(NN + 255) / 256, 256, 0, stream>>>(x, out, gw1, gb1,
                                                               gw2, gb2);
    }
}